// Round 8
// baseline (689.081 us; speedup 1.0000x reference)
//
#include <hip/hip_runtime.h>
#include <math.h>
#include <stdint.h>

#define N_NODES 50000
#define FEAT    256
#define EDGES   200000
#define HEADS   4
#define CH      128
#define HID     512   // HEADS*CH
#define NGRAPH  256
#define NCLS    10

typedef unsigned short ushort_t;
typedef unsigned int uint_t;
typedef __attribute__((ext_vector_type(8))) short bf16x8;
typedef __attribute__((ext_vector_type(4))) float f32x4;

__device__ __forceinline__ ushort_t f2bf(float f) {  // round-to-nearest-even
  uint_t u = __float_as_uint(f);
  u += 0x7FFF + ((u >> 16) & 1);
  return (ushort_t)(u >> 16);
}
__device__ __forceinline__ float bf2f(ushort_t h) {
  return __uint_as_float(((uint_t)h) << 16);
}
__device__ __forceinline__ void unpack8(uint4 w, float* f) {
  f[0] = bf2f((ushort_t)w.x); f[1] = bf2f((ushort_t)(w.x >> 16));
  f[2] = bf2f((ushort_t)w.y); f[3] = bf2f((ushort_t)(w.y >> 16));
  f[4] = bf2f((ushort_t)w.z); f[5] = bf2f((ushort_t)(w.z >> 16));
  f[6] = bf2f((ushort_t)w.w); f[7] = bf2f((ushort_t)(w.w >> 16));
}

// ---------------------------------------------------------------------------
// bf16 MFMA GEMM: C[M,N] = A[M,K] @ Bt[N,K]^T + bias (bf16 out)
// 128x128 tile, BK=32, 16 KB LDS. XCD-swizzled 1-D grid (A-tile stays in one
// XCD's L2: round-7 FETCH 180->34 MB). Fragment swizzle (r>>1)&3: bank
// pattern (r&1, slot) covers all 32 banks over 8 rows -> 2-way (free), vs
// round-7's (r&3) which was 4-way. Epilogue swizzle cl^(rq<<4) spreads the
// 4 rq-rows across bank octets (2-way); readback remaps chunk ci^(rq<<1).
// ---------------------------------------------------------------------------
__global__ __launch_bounds__(256) void gemm_bt(
    const ushort_t* __restrict__ A, const ushort_t* __restrict__ Bt,
    const float* __restrict__ bias, ushort_t* __restrict__ C, int ldc,
    int M, int K, int ncol) {
  __shared__ __align__(16) ushort_t smem[8192];   // 16 KB total
  ushort_t* sA = smem;                            // 128 x 32
  ushort_t* sB = smem + 4096;                     // 128 x 32
  const int tid = threadIdx.x;
  const int lane = tid & 63, wave = tid >> 6;
  const int wr = wave >> 1, wc = wave & 1;

  // XCD-aware decode: rt = grp*8 + (b%8), c = (b/8)%ncol
  int b = blockIdx.x;
  int per = ncol << 3;
  int grp = b / per;
  int rem = b - grp * per;
  int rloc = rem & 7;
  int c = rem >> 3;
  const int rowBase = (grp * 8 + rloc) * 128;
  const int colBase = c * 128;
  if (rowBase >= M) return;

  f32x4 acc[4][4] = {};

  for (int k0 = 0; k0 < K; k0 += 32) {
#pragma unroll
    for (int l = 0; l < 2; ++l) {
      int slot = l * 256 + tid;           // 0..511
      int rl = slot >> 2;                 // row/col 0..127
      int pos = slot & 3;                 // stored chunk slot
      int cg = pos ^ ((rl >> 1) & 3);     // swizzled global chunk
      {
        int row = rowBase + rl;
        row = row < M ? row : M - 1;      // clamp tail (epilogue guards)
        const ushort_t* gp = A + (size_t)row * K + k0 + cg * 8;
        __builtin_amdgcn_global_load_lds(
            (const __attribute__((address_space(1))) uint_t*)gp,
            (__attribute__((address_space(3))) uint_t*)(sA + slot * 8),
            16, 0, 0);
      }
      {
        int n = colBase + rl;
        const ushort_t* gp = Bt + (size_t)n * K + k0 + cg * 8;
        __builtin_amdgcn_global_load_lds(
            (const __attribute__((address_space(1))) uint_t*)gp,
            (__attribute__((address_space(3))) uint_t*)(sB + slot * 8),
            16, 0, 0);
      }
    }
    __syncthreads();
    const int fr = lane & 15, c0 = lane >> 4;
    bf16x8 af[4], bfr[4];
#pragma unroll
    for (int i = 0; i < 4; ++i) {
      int r = wr * 64 + i * 16 + fr;
      af[i] = *(const bf16x8*)(sA + r * 32 + ((c0 ^ ((r >> 1) & 3)) * 8));
      int n = wc * 64 + i * 16 + fr;
      bfr[i] = *(const bf16x8*)(sB + n * 32 + ((c0 ^ ((n >> 1) & 3)) * 8));
    }
#pragma unroll
    for (int i = 0; i < 4; ++i)
#pragma unroll
      for (int j = 0; j < 4; ++j)
        acc[i][j] = __builtin_amdgcn_mfma_f32_16x16x32_bf16(af[i], bfr[j], acc[i][j], 0, 0, 0);
    __syncthreads();
  }

  // Epilogue: per-wave LDS repack in two 32-row halves (4 KB/wave region).
  // C/D layout col=lane&15, row=(lane>>4)*4+reg (m89-verified).
  ushort_t* wbuf = smem + wave * 2048;    // 32 x 64 bf16
  const int rq = lane >> 4, fc = lane & 15;
  float bv[4];
#pragma unroll
  for (int j = 0; j < 4; ++j) bv[j] = bias[colBase + wc * 64 + j * 16 + fc];
#pragma unroll
  for (int h = 0; h < 2; ++h) {
#pragma unroll
    for (int ii = 0; ii < 2; ++ii) {
      int i = h * 2 + ii;
#pragma unroll
      for (int j = 0; j < 4; ++j)
#pragma unroll
        for (int r = 0; r < 4; ++r) {
          int rl = ii * 16 + rq * 4 + r;          // 0..31 ; (rl>>2)&3 == rq
          int cl = j * 16 + fc;                   // 0..63
          int cs = cl ^ (rq << 4);                // rq -> bank octet
          wbuf[rl * 64 + cs] = f2bf(acc[i][j][r] + bv[j]);
        }
    }
    // read back: lanes 0..7 cover all 32 banks (ci*4); remap chunk by rq
    int ci = lane & 7;
    int rbase = lane >> 3;                         // 0..7
#pragma unroll
    for (int rg = 0; rg < 4; ++rg) {
      int rr = rg * 8 + rbase;                     // 0..31
      int rowg = rowBase + wr * 64 + h * 32 + rr;
      int cg = ci ^ (((rr >> 2) & 3) << 1);
      uint4 val = *(const uint4*)(wbuf + rr * 64 + (ci << 3));
      if (rowg < M)
        *(uint4*)(C + (size_t)rowg * ldc + colBase + wc * 64 + cg * 8) = val;
    }
  }
}

// ---------------------------------------------------------------------------
// Prep: x -> bf16; weights -> transposed bf16 via 32x32 LDS tile transpose.
// W1t[2048][256]: n -> p=n>>10, hh=(n>>9)&1, sel=(n>>7)&3 (q,k,v,s),
//                 c=(2p+hh)*128+(n&127)
// W2t[1664][512]: n<768: heads 0,1 (q|k|v per 128); [768,896): skip (Ws2);
//                 n>=896: heads 2,3.
// ---------------------------------------------------------------------------
__global__ void cvt_bf16_kernel(const float* __restrict__ in, ushort_t* __restrict__ out, int n4) {
  int i = blockIdx.x * blockDim.x + threadIdx.x;
  if (i >= n4) return;
  float4 f = *(const float4*)(in + (size_t)i * 4);
  uint_t lo = (uint_t)f2bf(f.x) | ((uint_t)f2bf(f.y) << 16);
  uint_t hi = (uint_t)f2bf(f.z) | ((uint_t)f2bf(f.w) << 16);
  ((uint2*)out)[i] = make_uint2(lo, hi);
}

#define L1_W   (2048 * FEAT)
#define L2_W   (1664 * HID)
#define T1     512   // (2048/32)*(256/32)
#define T2     832   // (1664/32)*(512/32)

__global__ __launch_bounds__(256) void prep_tp(
    const float* __restrict__ Wq1, const float* __restrict__ Wk1,
    const float* __restrict__ Wv1, const float* __restrict__ Ws1,
    const float* __restrict__ Wq2, const float* __restrict__ Wk2,
    const float* __restrict__ Wv2, const float* __restrict__ Ws2,
    ushort_t* __restrict__ W1t, ushort_t* __restrict__ W2t) {
  __shared__ float tile[32][33];
  int t = blockIdx.x;
  const float* W; int ldw, c0, n0, k0, ldk; ushort_t* dst;
  if (t < T1) {
    int nb = t >> 3, kb = t & 7;
    n0 = nb * 32; k0 = kb * 32; ldk = FEAT; dst = W1t;
    int p = n0 >> 10, n1 = n0 & 1023, hh = n1 >> 9, sel = (n1 >> 7) & 3;
    c0 = (2 * p + hh) * CH + (n1 & (CH - 1));
    W = sel == 0 ? Wq1 : sel == 1 ? Wk1 : sel == 2 ? Wv1 : Ws1;
    ldw = HID;
  } else {
    t -= T1;
    int nb = t >> 4, kb = t & 15;
    n0 = nb * 32; k0 = kb * 32; ldk = HID; dst = W2t;
    if (n0 < 768 || n0 >= 896) {
      int n2 = (n0 < 768) ? n0 : n0 - 896;
      int hb = (n0 < 768) ? 0 : 2;
      int hh = hb + n2 / 384, r = n2 % 384, sel = r >> 7;
      c0 = hh * CH + (r & (CH - 1));
      W = sel == 0 ? Wq2 : sel == 1 ? Wk2 : Wv2;
      ldw = HID;
    } else {
      c0 = n0 - 768; W = Ws2; ldw = CH;
    }
  }
  int col = threadIdx.x & 31, rw = threadIdx.x >> 5;
#pragma unroll
  for (int ph = 0; ph < 4; ++ph) {
    int kk = rw + ph * 8;
    tile[kk][col] = W[(size_t)(k0 + kk) * ldw + c0 + col];   // coalesced read
  }
  __syncthreads();
#pragma unroll
  for (int ph = 0; ph < 4; ++ph) {
    int dn = rw + ph * 8;
    dst[(size_t)(n0 + dn) * ldk + k0 + col] = f2bf(tile[col][dn]);  // coalesced write
  }
}

__global__ void bias_kernel(
    const float* __restrict__ bq1, const float* __restrict__ bk1,
    const float* __restrict__ bv1, const float* __restrict__ bs1,
    const float* __restrict__ bq2, const float* __restrict__ bk2,
    const float* __restrict__ bv2, const float* __restrict__ bs2,
    float* __restrict__ Bh1, float* __restrict__ Bh2) {
  int n = blockIdx.x * blockDim.x + threadIdx.x;
  if (n < 2048) {
    int p = n >> 10, n1 = n & 1023, hh = n1 >> 9, sel = (n1 >> 7) & 3;
    int c = (2 * p + hh) * CH + (n1 & (CH - 1));
    const float* b = sel == 0 ? bq1 : sel == 1 ? bk1 : sel == 2 ? bv1 : bs1;
    Bh1[n] = b[c];
  } else {
    int n2 = n - 2048;
    if (n2 >= 1664) return;
    if (n2 < 768 || n2 >= 896) {
      int nn = (n2 < 768) ? n2 : n2 - 896;
      int hb = (n2 < 768) ? 0 : 2;
      int hh = hb + nn / 384, r = nn % 384, sel = r >> 7;
      int c = hh * CH + (r & (CH - 1));
      const float* b = sel == 0 ? bq2 : sel == 1 ? bk2 : bv2;
      Bh2[n2] = b[c];
    } else {
      Bh2[n2] = bs2[n2 - 768];
    }
  }
}

// ---------------------------------------------------------------------------
// CSR build: zero -> hist+bounds -> alloc (wave atomic) -> scatter
// ---------------------------------------------------------------------------
__global__ void zero_kernel(int* __restrict__ deg, int* __restrict__ counter,
                            int* __restrict__ gstart, int* __restrict__ gend) {
  int i = blockIdx.x * blockDim.x + threadIdx.x;
  if (i < N_NODES) deg[i] = 0;
  if (i < NGRAPH) { gstart[i] = 0; gend[i] = 0; }
  if (i == 0) counter[0] = 0;
}

__global__ void hist_bounds_kernel(const int* __restrict__ dst, int* __restrict__ deg,
                                   const int* __restrict__ batch,
                                   int* __restrict__ gstart, int* __restrict__ gend) {
  int t = blockIdx.x * blockDim.x + threadIdx.x;
  if (t < EDGES) atomicAdd(&deg[dst[t]], 1);
  if (t < N_NODES) {
    int b = batch[t];
    if (t == 0 || batch[t - 1] != b) gstart[b] = t;
    if (t == N_NODES - 1 || batch[t + 1] != b) gend[b] = t + 1;
  }
}

__global__ void alloc_kernel(const int* __restrict__ deg, int* __restrict__ counter,
                             int* __restrict__ start, int* __restrict__ cursor) {
  int i = blockIdx.x * blockDim.x + threadIdx.x;
  int lane = threadIdx.x & 63;
  int v = (i < N_NODES) ? deg[i] : 0;
  int sum = v;
#pragma unroll
  for (int off = 1; off < 64; off <<= 1) {
    int t = __shfl_up(sum, off);
    if (lane >= off) sum += t;
  }
  int excl = sum - v;
  int waveTot = __shfl(sum, 63);
  int base = 0;
  if (lane == 63) base = atomicAdd(counter, waveTot);
  base = __shfl(base, 63);
  if (i < N_NODES) {
    start[i] = base + excl;
    cursor[i] = base + excl;
  }
}

__global__ void scatter_kernel(const int* __restrict__ src, const int* __restrict__ dst,
                               int* __restrict__ cursor, int* __restrict__ csr) {
  int e = blockIdx.x * blockDim.x + threadIdx.x;
  if (e < EDGES) {
    int pos = atomicAdd(&cursor[dst[e]], 1);
    csr[pos] = src[e];
  }
}

// ---------------------------------------------------------------------------
// Attention core: one wave per node, TWO heads per edge-iteration.
// 4 x 16-lane groups process 4 edges in parallel (8 ch/lane, uint4 loads);
// shared csr load + same-row K/V for both heads; per-group online-softmax
// states merged at the end via 2 butterfly rounds over lane bits 4,5.
// Layout contract: q at qo, k at qo+128, v at qo+256 (stride 1024).
// ---------------------------------------------------------------------------
__device__ __forceinline__ void attn_node_dual(
    const ushort_t* __restrict__ buf, int qo0, int qo1,
    int i, int li, int g, int beg, int end, const int* __restrict__ csr,
    float* a0, float* a1, float& s0o, float& s1o) {
  const ushort_t* ip = buf + (size_t)i * 1024;
  float q0[8], q1[8];
  unpack8(*(const uint4*)(ip + qo0 + li * 8), q0);
  unpack8(*(const uint4*)(ip + qo1 + li * 8), q1);
  float m0 = -1e30f, s0 = 0.f, m1 = -1e30f, s1 = 0.f;
#pragma unroll
  for (int c = 0; c < 8; ++c) { a0[c] = 0.f; a1[c] = 0.f; }
  for (int e0 = beg; e0 < end; e0 += 4) {
    int eg = e0 + g;
    bool valid = eg < end;
    int j = csr[valid ? eg : beg];
    const ushort_t* jp = buf + (size_t)j * 1024;
    uint4 kw0 = *(const uint4*)(jp + qo0 + CH + li * 8);
    uint4 vw0 = *(const uint4*)(jp + qo0 + 2 * CH + li * 8);
    uint4 kw1 = *(const uint4*)(jp + qo1 + CH + li * 8);
    uint4 vw1 = *(const uint4*)(jp + qo1 + 2 * CH + li * 8);
    float kf[8];
    unpack8(kw0, kf);
    float p0 = q0[0]*kf[0]+q0[1]*kf[1]+q0[2]*kf[2]+q0[3]*kf[3]+
               q0[4]*kf[4]+q0[5]*kf[5]+q0[6]*kf[6]+q0[7]*kf[7];
    unpack8(kw1, kf);
    float p1 = q1[0]*kf[0]+q1[1]*kf[1]+q1[2]*kf[2]+q1[3]*kf[3]+
               q1[4]*kf[4]+q1[5]*kf[5]+q1[6]*kf[6]+q1[7]*kf[7];
#pragma unroll
    for (int ox = 1; ox <= 8; ox <<= 1) {
      p0 += __shfl_xor(p0, ox);
      p1 += __shfl_xor(p1, ox);
    }
    float al0 = valid ? p0 * 0.08838834764831845f : -1e30f;  // 1/sqrt(128)
    float al1 = valid ? p1 * 0.08838834764831845f : -1e30f;
    float vf[8];
    {
      float mn = fmaxf(m0, al0);
      float sc = expf(m0 - mn), w = valid ? expf(al0 - mn) : 0.f;
      unpack8(vw0, vf);
      s0 = s0 * sc + w;
#pragma unroll
      for (int c = 0; c < 8; ++c) a0[c] = a0[c] * sc + w * vf[c];
      m0 = mn;
    }
    {
      float mn = fmaxf(m1, al1);
      float sc = expf(m1 - mn), w = valid ? expf(al1 - mn) : 0.f;
      unpack8(vw1, vf);
      s1 = s1 * sc + w;
#pragma unroll
      for (int c = 0; c < 8; ++c) a1[c] = a1[c] * sc + w * vf[c];
      m1 = mn;
    }
  }
#pragma unroll
  for (int ox = 16; ox <= 32; ox <<= 1) {
    {
      float mo = __shfl_xor(m0, ox), so = __shfl_xor(s0, ox);
      float mn = fmaxf(m0, mo);
      float sc1 = expf(m0 - mn), sc2 = expf(mo - mn);
      s0 = s0 * sc1 + so * sc2;
#pragma unroll
      for (int c = 0; c < 8; ++c) {
        float ao = __shfl_xor(a0[c], ox);
        a0[c] = a0[c] * sc1 + ao * sc2;
      }
      m0 = mn;
    }
    {
      float mo = __shfl_xor(m1, ox), so = __shfl_xor(s1, ox);
      float mn = fmaxf(m1, mo);
      float sc1 = expf(m1 - mn), sc2 = expf(mo - mn);
      s1 = s1 * sc1 + so * sc2;
#pragma unroll
      for (int c = 0; c < 8; ++c) {
        float ao = __shfl_xor(a1[c], ox);
        a1[c] = a1[c] * sc1 + ao * sc2;
      }
      m1 = mn;
    }
  }
  s0o = s0; s1o = s1;
}

// layer 1 (pair p): layout [q|k|v|s] x 2 heads, stride 1024.
// Fused skip-add + ELU; writes H1b cols (2p+hh)*128 for hh=0,1.
__global__ __launch_bounds__(256) void attn1_kernel(
    const ushort_t* __restrict__ QKVS2, const int* __restrict__ start,
    const int* __restrict__ deg, const int* __restrict__ csr,
    ushort_t* __restrict__ H1b, int p) {
  int wave = threadIdx.x >> 6, lane = threadIdx.x & 63;
  int li = lane & 15, g = lane >> 4;
  int i = blockIdx.x * 4 + wave;
  if (i >= N_NODES) return;
  int beg = start[i], end = beg + deg[i];
  float a0[8], a1[8], s0, s1;
  attn_node_dual(QKVS2, 0, 512, i, li, g, beg, end, csr, a0, a1, s0, s1);
  if (g != 0) return;
  const ushort_t* ip = QKVS2 + (size_t)i * 1024;
#pragma unroll
  for (int hh = 0; hh < 2; ++hh) {
    float* a = hh ? a1 : a0;
    float inv = 1.f / ((hh ? s1 : s0) + 1e-16f);
    float sk[8];
    unpack8(*(const uint4*)(ip + hh * 512 + 384 + li * 8), sk);
    uint4 ow;
    uint_t* op = (uint_t*)&ow;
#pragma unroll
    for (int c = 0; c < 4; ++c) {
      float o0 = a[2 * c] * inv + sk[2 * c];
      float o1 = a[2 * c + 1] * inv + sk[2 * c + 1];
      o0 = o0 > 0.f ? o0 : expm1f(o0);
      o1 = o1 > 0.f ? o1 : expm1f(o1);
      op[c] = (uint_t)f2bf(o0) | ((uint_t)f2bf(o1) << 16);
    }
    *(uint4*)(H1b + (size_t)i * HID + (2 * p + hh) * CH + li * 8) = ow;
  }
}

// layer 2: layout [q0|k0|v0 | q1|k1|v1 | skip], stride 1024.
// first=1: S2 = skip + 0.25*(m0+m1); else S2 += 0.25*(m0+m1).
__global__ __launch_bounds__(256) void attn2_kernel(
    const ushort_t* __restrict__ buf, const int* __restrict__ start,
    const int* __restrict__ deg, const int* __restrict__ csr,
    float* __restrict__ S2, int first) {
  int wave = threadIdx.x >> 6, lane = threadIdx.x & 63;
  int li = lane & 15, g = lane >> 4;
  int i = blockIdx.x * 4 + wave;
  if (i >= N_NODES) return;
  int beg = start[i], end = beg + deg[i];
  float a0[8], a1[8], s0, s1;
  attn_node_dual(buf, 0, 384, i, li, g, beg, end, csr, a0, a1, s0, s1);
  if (g != 0) return;
  float inv0 = 0.25f / (s0 + 1e-16f), inv1 = 0.25f / (s1 + 1e-16f);
  float* sp = S2 + (size_t)i * CH + li * 8;
  if (first) {
    float sk[8];
    unpack8(*(const uint4*)(buf + (size_t)i * 1024 + 768 + li * 8), sk);
#pragma unroll
    for (int c = 0; c < 8; ++c) sp[c] = sk[c] + a0[c] * inv0 + a1[c] * inv1;
  } else {
#pragma unroll
    for (int c = 0; c < 8; ++c) sp[c] += a0[c] * inv0 + a1[c] * inv1;
  }
}

// ---------------------------------------------------------------------------
// Fused pool (segment loop, no atomics — batch is sorted) + ELU + classifier
// + log_softmax. One block of 256 per graph: 2 rows x 128 ch.
// ---------------------------------------------------------------------------
__global__ __launch_bounds__(256) void pool_cls(
    const float* __restrict__ S2, const int* __restrict__ gstart,
    const int* __restrict__ gend, const float* __restrict__ Wfc,
    const float* __restrict__ bfc, float* __restrict__ out) {
  int g = blockIdx.x;
  int t = threadIdx.x;
  int c = t & (CH - 1), rr = t >> 7;
  int s0 = gstart[g], e0 = gend[g];
  float sum = 0.f;
  for (int i = s0 + rr; i < e0; i += 2) {
    float v = S2[(size_t)i * CH + c];
    v = v > 0.f ? v : expm1f(v);
    sum += v;
  }
  __shared__ float sh[256];
  __shared__ float p[CH];
  __shared__ float red[CH];
  __shared__ float logits[NCLS];
  sh[t] = sum;
  __syncthreads();
  if (t < CH) {
    float cnt = fmaxf((float)(e0 - s0), 1.f);
    p[t] = (sh[t] + sh[t + CH]) / cnt;
  }
  for (int cc = 0; cc < NCLS; ++cc) {
    __syncthreads();
    if (t < CH) red[t] = p[t] * Wfc[t * NCLS + cc];
    __syncthreads();
    for (int off = 64; off > 0; off >>= 1) {
      if (t < off) red[t] += red[t + off];
      __syncthreads();
    }
    if (t == 0) logits[cc] = red[0] + bfc[cc];
  }
  __syncthreads();
  if (t == 0) {
    float mx = -INFINITY;
    for (int cc = 0; cc < NCLS; ++cc) mx = fmaxf(mx, logits[cc]);
    float se = 0.f;
    for (int cc = 0; cc < NCLS; ++cc) se += expf(logits[cc] - mx);
    float ls = mx + logf(se);
    for (int cc = 0; cc < NCLS; ++cc) out[g * NCLS + cc] = logits[cc] - ls;
  }
}

// ---------------------------------------------------------------------------
extern "C" void kernel_launch(void* const* d_in, const int* in_sizes, int n_in,
                              void* d_out, int out_size, void* d_ws, size_t ws_size,
                              hipStream_t stream) {
  const float* x    = (const float*)d_in[0];
  const int*   ei   = (const int*)d_in[1];
  const int*   batch= (const int*)d_in[2];
  const float* Wq1 = (const float*)d_in[3];  const float* bq1 = (const float*)d_in[4];
  const float* Wk1 = (const float*)d_in[5];  const float* bk1 = (const float*)d_in[6];
  const float* Wv1 = (const float*)d_in[7];  const float* bv1 = (const float*)d_in[8];
  const float* Ws1 = (const float*)d_in[9];  const float* bs1 = (const float*)d_in[10];
  const float* Wq2 = (const float*)d_in[11]; const float* bq2 = (const float*)d_in[12];
  const float* Wk2 = (const float*)d_in[13]; const float* bk2 = (const float*)d_in[14];
  const float* Wv2 = (const float*)d_in[15]; const float* bv2 = (const float*)d_in[16];
  const float* Ws2 = (const float*)d_in[17]; const float* bs2 = (const float*)d_in[18];
  const float* Wfc = (const float*)d_in[19]; const float* bfc = (const float*)d_in[20];
  float* out = (float*)d_out;

  // Workspace (~183 MB). S2 (fp32 N*128 = 25.6MB) aliases xb (dead after L1 GEMMs).
  ushort_t* xb   = (ushort_t*)d_ws;                    // N x 256 bf16
  float*    S2   = (float*)d_ws;                       // N x 128 fp32 (aliases xb)
  ushort_t* BIG  = xb + (size_t)N_NODES * FEAT;        // N x 1024 bf16
  ushort_t* H1b  = BIG + (size_t)N_NODES * 1024;       // N x 512 bf16
  ushort_t* W1t  = H1b + (size_t)N_NODES * HID;        // 2048*256
  float*    Bh1  = (float*)(W1t + L1_W);               // 2048
  ushort_t* W2t  = (ushort_t*)(Bh1 + 2048);            // 1664*512
  float*    Bh2  = (float*)(W2t + L2_W);               // 1664
  int* deg    = (int*)(Bh2 + 1664);
  int* start  = deg + N_NODES;
  int* cursor = start + N_NODES;
  int* csr    = cursor + N_NODES;
  int* gstart = csr + EDGES;
  int* gend   = gstart + NGRAPH;
  int* counter= gend + NGRAPH;

  const int* srcp = ei;
  const int* dstp = ei + EDGES;

  // ---- prep ----
  cvt_bf16_kernel<<<(N_NODES * FEAT / 4 + 255) / 256, 256, 0, stream>>>(x, xb, N_NODES * FEAT / 4);
  prep_tp<<<T1 + T2, 256, 0, stream>>>(Wq1, Wk1, Wv1, Ws1, Wq2, Wk2, Wv2, Ws2, W1t, W2t);
  bias_kernel<<<(2048 + 1664 + 255) / 256, 256, 0, stream>>>(
      bq1, bk1, bv1, bs1, bq2, bk2, bv2, bs2, Bh1, Bh2);

  // ---- CSR build ----
  zero_kernel<<<(N_NODES + 255) / 256, 256, 0, stream>>>(deg, counter, gstart, gend);
  hist_bounds_kernel<<<(EDGES + 255) / 256, 256, 0, stream>>>(dstp, deg, batch, gstart, gend);
  alloc_kernel<<<(N_NODES + 255) / 256, 256, 0, stream>>>(deg, counter, start, cursor);
  scatter_kernel<<<(EDGES + 255) / 256, 256, 0, stream>>>(srcp, dstp, cursor, csr);

  const int gx8 = 49 * 8;               // 392 row tiles (padded; kernel guards)
  const int ga = (N_NODES + 3) / 4;     // 12500

  // ---- layer 1: per head-pair, GEMM (1024 cols) + dual-head attention ----
  for (int p = 0; p < 2; ++p) {
    gemm_bt<<<gx8 * 8, 256, 0, stream>>>(
        xb, W1t + (size_t)p * 1024 * FEAT, Bh1 + p * 1024, BIG, 1024, N_NODES, FEAT, 8);
    attn1_kernel<<<ga, 256, 0, stream>>>(BIG, start, deg, csr, H1b, p);
  }

  // ---- layer 2: pair0 GEMM includes skip cols (896, ldc=1024) ----
  gemm_bt<<<gx8 * 7, 256, 0, stream>>>(
      H1b, W2t, Bh2, BIG, 1024, N_NODES, HID, 7);
  attn2_kernel<<<ga, 256, 0, stream>>>(BIG, start, deg, csr, S2, 1);
  gemm_bt<<<gx8 * 6, 256, 0, stream>>>(
      H1b, W2t + (size_t)896 * HID, Bh2 + 896, BIG, 1024, N_NODES, HID, 6);
  attn2_kernel<<<ga, 256, 0, stream>>>(BIG, start, deg, csr, S2, 0);

  // ---- fused pool + classify ----
  pool_cls<<<NGRAPH, 256, 0, stream>>>(S2, gstart, gend, Wfc, bfc, out);
}

// Round 9
// 674.856 us; speedup vs baseline: 1.0211x; 1.0211x over previous
//
#include <hip/hip_runtime.h>
#include <math.h>
#include <stdint.h>

#define N_NODES 50000
#define FEAT    256
#define EDGES   200000
#define HEADS   4
#define CH      128
#define HID     512   // HEADS*CH
#define NGRAPH  256
#define NCLS    10

typedef unsigned short ushort_t;
typedef unsigned int uint_t;
typedef __attribute__((ext_vector_type(8))) short bf16x8;
typedef __attribute__((ext_vector_type(4))) float f32x4;

__device__ __forceinline__ ushort_t f2bf(float f) {  // round-to-nearest-even
  uint_t u = __float_as_uint(f);
  u += 0x7FFF + ((u >> 16) & 1);
  return (ushort_t)(u >> 16);
}
__device__ __forceinline__ float bf2f(ushort_t h) {
  return __uint_as_float(((uint_t)h) << 16);
}
__device__ __forceinline__ void unpack8(uint4 w, float* f) {
  f[0] = bf2f((ushort_t)w.x); f[1] = bf2f((ushort_t)(w.x >> 16));
  f[2] = bf2f((ushort_t)w.y); f[3] = bf2f((ushort_t)(w.y >> 16));
  f[4] = bf2f((ushort_t)w.z); f[5] = bf2f((ushort_t)(w.z >> 16));
  f[6] = bf2f((ushort_t)w.w); f[7] = bf2f((ushort_t)(w.w >> 16));
}

// ---------------------------------------------------------------------------
// bf16 MFMA GEMM: C[M,N] = A[M,K] @ Bt[N,K]^T + bias (bf16 out)
// 128x128 tile, BK=32, 16 KB LDS. XCD-swizzled 1-D grid (round-7: FETCH
// 180->34 MB). Fragment swizzle (r>>1)&3 and epilogue swizzle rq<<4 are
// 2-way max (round-8: SQ_LDS_BANK_CONFLICT == 0). Do not touch.
// ---------------------------------------------------------------------------
__global__ __launch_bounds__(256) void gemm_bt(
    const ushort_t* __restrict__ A, const ushort_t* __restrict__ Bt,
    const float* __restrict__ bias, ushort_t* __restrict__ C, int ldc,
    int M, int K, int ncol) {
  __shared__ __align__(16) ushort_t smem[8192];   // 16 KB total
  ushort_t* sA = smem;                            // 128 x 32
  ushort_t* sB = smem + 4096;                     // 128 x 32
  const int tid = threadIdx.x;
  const int lane = tid & 63, wave = tid >> 6;
  const int wr = wave >> 1, wc = wave & 1;

  // XCD-aware decode: rt = grp*8 + (b%8), c = (b/8)%ncol
  int b = blockIdx.x;
  int per = ncol << 3;
  int grp = b / per;
  int rem = b - grp * per;
  int rloc = rem & 7;
  int c = rem >> 3;
  const int rowBase = (grp * 8 + rloc) * 128;
  const int colBase = c * 128;
  if (rowBase >= M) return;

  f32x4 acc[4][4] = {};

  for (int k0 = 0; k0 < K; k0 += 32) {
#pragma unroll
    for (int l = 0; l < 2; ++l) {
      int slot = l * 256 + tid;           // 0..511
      int rl = slot >> 2;                 // row/col 0..127
      int pos = slot & 3;                 // stored chunk slot
      int cg = pos ^ ((rl >> 1) & 3);     // swizzled global chunk
      {
        int row = rowBase + rl;
        row = row < M ? row : M - 1;      // clamp tail (epilogue guards)
        const ushort_t* gp = A + (size_t)row * K + k0 + cg * 8;
        __builtin_amdgcn_global_load_lds(
            (const __attribute__((address_space(1))) uint_t*)gp,
            (__attribute__((address_space(3))) uint_t*)(sA + slot * 8),
            16, 0, 0);
      }
      {
        int n = colBase + rl;
        const ushort_t* gp = Bt + (size_t)n * K + k0 + cg * 8;
        __builtin_amdgcn_global_load_lds(
            (const __attribute__((address_space(1))) uint_t*)gp,
            (__attribute__((address_space(3))) uint_t*)(sB + slot * 8),
            16, 0, 0);
      }
    }
    __syncthreads();
    const int fr = lane & 15, c0 = lane >> 4;
    bf16x8 af[4], bfr[4];
#pragma unroll
    for (int i = 0; i < 4; ++i) {
      int r = wr * 64 + i * 16 + fr;
      af[i] = *(const bf16x8*)(sA + r * 32 + ((c0 ^ ((r >> 1) & 3)) * 8));
      int n = wc * 64 + i * 16 + fr;
      bfr[i] = *(const bf16x8*)(sB + n * 32 + ((c0 ^ ((n >> 1) & 3)) * 8));
    }
#pragma unroll
    for (int i = 0; i < 4; ++i)
#pragma unroll
      for (int j = 0; j < 4; ++j)
        acc[i][j] = __builtin_amdgcn_mfma_f32_16x16x32_bf16(af[i], bfr[j], acc[i][j], 0, 0, 0);
    __syncthreads();
  }

  // Epilogue: per-wave LDS repack in two 32-row halves (4 KB/wave region).
  // C/D layout col=lane&15, row=(lane>>4)*4+reg (m89-verified).
  ushort_t* wbuf = smem + wave * 2048;    // 32 x 64 bf16
  const int rq = lane >> 4, fc = lane & 15;
  float bv[4];
#pragma unroll
  for (int j = 0; j < 4; ++j) bv[j] = bias[colBase + wc * 64 + j * 16 + fc];
#pragma unroll
  for (int h = 0; h < 2; ++h) {
#pragma unroll
    for (int ii = 0; ii < 2; ++ii) {
      int i = h * 2 + ii;
#pragma unroll
      for (int j = 0; j < 4; ++j)
#pragma unroll
        for (int r = 0; r < 4; ++r) {
          int rl = ii * 16 + rq * 4 + r;          // 0..31 ; (rl>>2)&3 == rq
          int cl = j * 16 + fc;                   // 0..63
          int cs = cl ^ (rq << 4);                // rq -> bank octet
          wbuf[rl * 64 + cs] = f2bf(acc[i][j][r] + bv[j]);
        }
    }
    // read back: lanes 0..7 cover all 32 banks (ci*4); remap chunk by rq
    int ci = lane & 7;
    int rbase = lane >> 3;                         // 0..7
#pragma unroll
    for (int rg = 0; rg < 4; ++rg) {
      int rr = rg * 8 + rbase;                     // 0..31
      int rowg = rowBase + wr * 64 + h * 32 + rr;
      int cg = ci ^ (((rr >> 2) & 3) << 1);
      uint4 val = *(const uint4*)(wbuf + rr * 64 + (ci << 3));
      if (rowg < M)
        *(uint4*)(C + (size_t)rowg * ldc + colBase + wc * 64 + cg * 8) = val;
    }
  }
}

// ---------------------------------------------------------------------------
// Prep: x -> bf16; weights -> transposed bf16 via 32x32 LDS tile transpose.
// W1t[2048][256]: n -> p=n>>10, hh=(n>>9)&1, sel=(n>>7)&3 (q,k,v,s),
//                 c=(2p+hh)*128+(n&127)
// W2t[1664][512]: n<768: heads 0,1 (q|k|v per 128); [768,896): skip (Ws2);
//                 n>=896: heads 2,3.
// ---------------------------------------------------------------------------
__global__ void cvt_bf16_kernel(const float* __restrict__ in, ushort_t* __restrict__ out, int n4) {
  int i = blockIdx.x * blockDim.x + threadIdx.x;
  if (i >= n4) return;
  float4 f = *(const float4*)(in + (size_t)i * 4);
  uint_t lo = (uint_t)f2bf(f.x) | ((uint_t)f2bf(f.y) << 16);
  uint_t hi = (uint_t)f2bf(f.z) | ((uint_t)f2bf(f.w) << 16);
  ((uint2*)out)[i] = make_uint2(lo, hi);
}

#define L1_W   (2048 * FEAT)
#define L2_W   (1664 * HID)
#define T1     512   // (2048/32)*(256/32)
#define T2     832   // (1664/32)*(512/32)

__global__ __launch_bounds__(256) void prep_tp(
    const float* __restrict__ Wq1, const float* __restrict__ Wk1,
    const float* __restrict__ Wv1, const float* __restrict__ Ws1,
    const float* __restrict__ Wq2, const float* __restrict__ Wk2,
    const float* __restrict__ Wv2, const float* __restrict__ Ws2,
    ushort_t* __restrict__ W1t, ushort_t* __restrict__ W2t) {
  __shared__ float tile[32][33];
  int t = blockIdx.x;
  const float* W; int ldw, c0, n0, k0, ldk; ushort_t* dst;
  if (t < T1) {
    int nb = t >> 3, kb = t & 7;
    n0 = nb * 32; k0 = kb * 32; ldk = FEAT; dst = W1t;
    int p = n0 >> 10, n1 = n0 & 1023, hh = n1 >> 9, sel = (n1 >> 7) & 3;
    c0 = (2 * p + hh) * CH + (n1 & (CH - 1));
    W = sel == 0 ? Wq1 : sel == 1 ? Wk1 : sel == 2 ? Wv1 : Ws1;
    ldw = HID;
  } else {
    t -= T1;
    int nb = t >> 4, kb = t & 15;
    n0 = nb * 32; k0 = kb * 32; ldk = HID; dst = W2t;
    if (n0 < 768 || n0 >= 896) {
      int n2 = (n0 < 768) ? n0 : n0 - 896;
      int hb = (n0 < 768) ? 0 : 2;
      int hh = hb + n2 / 384, r = n2 % 384, sel = r >> 7;
      c0 = hh * CH + (r & (CH - 1));
      W = sel == 0 ? Wq2 : sel == 1 ? Wk2 : Wv2;
      ldw = HID;
    } else {
      c0 = n0 - 768; W = Ws2; ldw = CH;
    }
  }
  int col = threadIdx.x & 31, rw = threadIdx.x >> 5;
#pragma unroll
  for (int ph = 0; ph < 4; ++ph) {
    int kk = rw + ph * 8;
    tile[kk][col] = W[(size_t)(k0 + kk) * ldw + c0 + col];   // coalesced read
  }
  __syncthreads();
#pragma unroll
  for (int ph = 0; ph < 4; ++ph) {
    int dn = rw + ph * 8;
    dst[(size_t)(n0 + dn) * ldk + k0 + col] = f2bf(tile[col][dn]);  // coalesced write
  }
}

__global__ void bias_kernel(
    const float* __restrict__ bq1, const float* __restrict__ bk1,
    const float* __restrict__ bv1, const float* __restrict__ bs1,
    const float* __restrict__ bq2, const float* __restrict__ bk2,
    const float* __restrict__ bv2, const float* __restrict__ bs2,
    float* __restrict__ Bh1, float* __restrict__ Bh2) {
  int n = blockIdx.x * blockDim.x + threadIdx.x;
  if (n < 2048) {
    int p = n >> 10, n1 = n & 1023, hh = n1 >> 9, sel = (n1 >> 7) & 3;
    int c = (2 * p + hh) * CH + (n1 & (CH - 1));
    const float* b = sel == 0 ? bq1 : sel == 1 ? bk1 : sel == 2 ? bv1 : bs1;
    Bh1[n] = b[c];
  } else {
    int n2 = n - 2048;
    if (n2 >= 1664) return;
    if (n2 < 768 || n2 >= 896) {
      int nn = (n2 < 768) ? n2 : n2 - 896;
      int hb = (n2 < 768) ? 0 : 2;
      int hh = hb + nn / 384, r = nn % 384, sel = r >> 7;
      int c = hh * CH + (r & (CH - 1));
      const float* b = sel == 0 ? bq2 : sel == 1 ? bk2 : bv2;
      Bh2[n2] = b[c];
    } else {
      Bh2[n2] = bs2[n2 - 768];
    }
  }
}

// ---------------------------------------------------------------------------
// CSR build: zero -> hist+bounds -> alloc (wave atomic) -> scatter
// ---------------------------------------------------------------------------
__global__ void zero_kernel(int* __restrict__ deg, int* __restrict__ counter,
                            int* __restrict__ gstart, int* __restrict__ gend) {
  int i = blockIdx.x * blockDim.x + threadIdx.x;
  if (i < N_NODES) deg[i] = 0;
  if (i < NGRAPH) { gstart[i] = 0; gend[i] = 0; }
  if (i == 0) counter[0] = 0;
}

__global__ void hist_bounds_kernel(const int* __restrict__ dst, int* __restrict__ deg,
                                   const int* __restrict__ batch,
                                   int* __restrict__ gstart, int* __restrict__ gend) {
  int t = blockIdx.x * blockDim.x + threadIdx.x;
  if (t < EDGES) atomicAdd(&deg[dst[t]], 1);
  if (t < N_NODES) {
    int b = batch[t];
    if (t == 0 || batch[t - 1] != b) gstart[b] = t;
    if (t == N_NODES - 1 || batch[t + 1] != b) gend[b] = t + 1;
  }
}

__global__ void alloc_kernel(const int* __restrict__ deg, int* __restrict__ counter,
                             int* __restrict__ start, int* __restrict__ cursor) {
  int i = blockIdx.x * blockDim.x + threadIdx.x;
  int lane = threadIdx.x & 63;
  int v = (i < N_NODES) ? deg[i] : 0;
  int sum = v;
#pragma unroll
  for (int off = 1; off < 64; off <<= 1) {
    int t = __shfl_up(sum, off);
    if (lane >= off) sum += t;
  }
  int excl = sum - v;
  int waveTot = __shfl(sum, 63);
  int base = 0;
  if (lane == 63) base = atomicAdd(counter, waveTot);
  base = __shfl(base, 63);
  if (i < N_NODES) {
    start[i] = base + excl;
    cursor[i] = base + excl;
  }
}

__global__ void scatter_kernel(const int* __restrict__ src, const int* __restrict__ dst,
                               int* __restrict__ cursor, int* __restrict__ csr) {
  int e = blockIdx.x * blockDim.x + threadIdx.x;
  if (e < EDGES) {
    int pos = atomicAdd(&cursor[dst[e]], 1);
    csr[pos] = src[e];
  }
}

// ---------------------------------------------------------------------------
// Attention cores. Gather-latency-bound (random 256B granules over 102 MB):
// maximize waves in flight. attn1: one wave per (node, head) — single-head
// core. attn2: one wave per node, dual-head core (same wave count as a head
// loop but 2x the loads in flight). 4 x 16-lane groups process 4 edges in
// parallel; per-group online-softmax states merged via 2 butterfly rounds.
// ---------------------------------------------------------------------------
__device__ __forceinline__ void attn_node_head(
    const ushort_t* __restrict__ buf, int off,
    int i, int li, int g, int beg, int end, const int* __restrict__ csr,
    float* a, float& sout) {
  float q[8];
  unpack8(*(const uint4*)(buf + (size_t)i * 1024 + off + li * 8), q);
  float m = -1e30f, s = 0.f;
#pragma unroll
  for (int c = 0; c < 8; ++c) a[c] = 0.f;
  for (int e0 = beg; e0 < end; e0 += 4) {
    int eg = e0 + g;
    bool valid = eg < end;
    int j = csr[valid ? eg : beg];
    const ushort_t* jp = buf + (size_t)j * 1024 + off;
    uint4 kw = *(const uint4*)(jp + CH + li * 8);
    uint4 vw = *(const uint4*)(jp + 2 * CH + li * 8);
    float kf[8]; unpack8(kw, kf);
    float p = q[0]*kf[0]+q[1]*kf[1]+q[2]*kf[2]+q[3]*kf[3]+
              q[4]*kf[4]+q[5]*kf[5]+q[6]*kf[6]+q[7]*kf[7];
    p += __shfl_xor(p, 1);
    p += __shfl_xor(p, 2);
    p += __shfl_xor(p, 4);
    p += __shfl_xor(p, 8);
    float alpha = valid ? p * 0.08838834764831845f : -1e30f;  // 1/sqrt(128)
    float mn = fmaxf(m, alpha);
    float sc = expf(m - mn);
    float w = valid ? expf(alpha - mn) : 0.f;
    float vf[8]; unpack8(vw, vf);
    s = s * sc + w;
#pragma unroll
    for (int c = 0; c < 8; ++c) a[c] = a[c] * sc + w * vf[c];
    m = mn;
  }
#pragma unroll
  for (int ox = 16; ox <= 32; ox <<= 1) {
    float mo = __shfl_xor(m, ox);
    float so = __shfl_xor(s, ox);
    float mn = fmaxf(m, mo);
    float sc1 = expf(m - mn), sc2 = expf(mo - mn);
    s = s * sc1 + so * sc2;
#pragma unroll
    for (int c = 0; c < 8; ++c) {
      float ao = __shfl_xor(a[c], ox);
      a[c] = a[c] * sc1 + ao * sc2;
    }
    m = mn;
  }
  sout = s;
}

__device__ __forceinline__ void attn_node_dual(
    const ushort_t* __restrict__ buf, int qo0, int qo1,
    int i, int li, int g, int beg, int end, const int* __restrict__ csr,
    float* a0, float* a1, float& s0o, float& s1o) {
  const ushort_t* ip = buf + (size_t)i * 1024;
  float q0[8], q1[8];
  unpack8(*(const uint4*)(ip + qo0 + li * 8), q0);
  unpack8(*(const uint4*)(ip + qo1 + li * 8), q1);
  float m0 = -1e30f, s0 = 0.f, m1 = -1e30f, s1 = 0.f;
#pragma unroll
  for (int c = 0; c < 8; ++c) { a0[c] = 0.f; a1[c] = 0.f; }
  for (int e0 = beg; e0 < end; e0 += 4) {
    int eg = e0 + g;
    bool valid = eg < end;
    int j = csr[valid ? eg : beg];
    const ushort_t* jp = buf + (size_t)j * 1024;
    uint4 kw0 = *(const uint4*)(jp + qo0 + CH + li * 8);
    uint4 vw0 = *(const uint4*)(jp + qo0 + 2 * CH + li * 8);
    uint4 kw1 = *(const uint4*)(jp + qo1 + CH + li * 8);
    uint4 vw1 = *(const uint4*)(jp + qo1 + 2 * CH + li * 8);
    float kf[8];
    unpack8(kw0, kf);
    float p0 = q0[0]*kf[0]+q0[1]*kf[1]+q0[2]*kf[2]+q0[3]*kf[3]+
               q0[4]*kf[4]+q0[5]*kf[5]+q0[6]*kf[6]+q0[7]*kf[7];
    unpack8(kw1, kf);
    float p1 = q1[0]*kf[0]+q1[1]*kf[1]+q1[2]*kf[2]+q1[3]*kf[3]+
               q1[4]*kf[4]+q1[5]*kf[5]+q1[6]*kf[6]+q1[7]*kf[7];
#pragma unroll
    for (int ox = 1; ox <= 8; ox <<= 1) {
      p0 += __shfl_xor(p0, ox);
      p1 += __shfl_xor(p1, ox);
    }
    float al0 = valid ? p0 * 0.08838834764831845f : -1e30f;  // 1/sqrt(128)
    float al1 = valid ? p1 * 0.08838834764831845f : -1e30f;
    float vf[8];
    {
      float mn = fmaxf(m0, al0);
      float sc = expf(m0 - mn), w = valid ? expf(al0 - mn) : 0.f;
      unpack8(vw0, vf);
      s0 = s0 * sc + w;
#pragma unroll
      for (int c = 0; c < 8; ++c) a0[c] = a0[c] * sc + w * vf[c];
      m0 = mn;
    }
    {
      float mn = fmaxf(m1, al1);
      float sc = expf(m1 - mn), w = valid ? expf(al1 - mn) : 0.f;
      unpack8(vw1, vf);
      s1 = s1 * sc + w;
#pragma unroll
      for (int c = 0; c < 8; ++c) a1[c] = a1[c] * sc + w * vf[c];
      m1 = mn;
    }
  }
#pragma unroll
  for (int ox = 16; ox <= 32; ox <<= 1) {
    {
      float mo = __shfl_xor(m0, ox), so = __shfl_xor(s0, ox);
      float mn = fmaxf(m0, mo);
      float sc1 = expf(m0 - mn), sc2 = expf(mo - mn);
      s0 = s0 * sc1 + so * sc2;
#pragma unroll
      for (int c = 0; c < 8; ++c) {
        float ao = __shfl_xor(a0[c], ox);
        a0[c] = a0[c] * sc1 + ao * sc2;
      }
      m0 = mn;
    }
    {
      float mo = __shfl_xor(m1, ox), so = __shfl_xor(s1, ox);
      float mn = fmaxf(m1, mo);
      float sc1 = expf(m1 - mn), sc2 = expf(mo - mn);
      s1 = s1 * sc1 + so * sc2;
#pragma unroll
      for (int c = 0; c < 8; ++c) {
        float ao = __shfl_xor(a1[c], ox);
        a1[c] = a1[c] * sc1 + ao * sc2;
      }
      m1 = mn;
    }
  }
  s0o = s0; s1o = s1;
}

// layer 1 (pair p, hh = blockIdx.y): layout [q|k|v|s] x 2 heads, stride 1024.
// One wave per (node, head). Fused skip-add + ELU; writes H1b col (2p+hh)*128.
__global__ __launch_bounds__(256) void attn1_kernel(
    const ushort_t* __restrict__ QKVS2, const int* __restrict__ start,
    const int* __restrict__ deg, const int* __restrict__ csr,
    ushort_t* __restrict__ H1b, int p) {
  int wave = threadIdx.x >> 6, lane = threadIdx.x & 63;
  int li = lane & 15, g = lane >> 4;
  int i = blockIdx.x * 4 + wave;
  if (i >= N_NODES) return;
  int hh = blockIdx.y;
  int beg = start[i], end = beg + deg[i];
  float a[8], s;
  attn_node_head(QKVS2, hh * 512, i, li, g, beg, end, csr, a, s);
  if (g != 0) return;
  float inv = 1.f / (s + 1e-16f);
  float sk[8];
  unpack8(*(const uint4*)(QKVS2 + (size_t)i * 1024 + hh * 512 + 384 + li * 8), sk);
  uint4 ow;
  uint_t* op = (uint_t*)&ow;
#pragma unroll
  for (int c = 0; c < 4; ++c) {
    float o0 = a[2 * c] * inv + sk[2 * c];
    float o1 = a[2 * c + 1] * inv + sk[2 * c + 1];
    o0 = o0 > 0.f ? o0 : expm1f(o0);
    o1 = o1 > 0.f ? o1 : expm1f(o1);
    op[c] = (uint_t)f2bf(o0) | ((uint_t)f2bf(o1) << 16);
  }
  *(uint4*)(H1b + (size_t)i * HID + (2 * p + hh) * CH + li * 8) = ow;
}

// layer 2: layout [q0|k0|v0 | q1|k1|v1 | skip], stride 1024. Dual-head.
// first=1: S2 = skip + 0.25*(m0+m1); else S2 += 0.25*(m0+m1).
__global__ __launch_bounds__(256) void attn2_kernel(
    const ushort_t* __restrict__ buf, const int* __restrict__ start,
    const int* __restrict__ deg, const int* __restrict__ csr,
    float* __restrict__ S2, int first) {
  int wave = threadIdx.x >> 6, lane = threadIdx.x & 63;
  int li = lane & 15, g = lane >> 4;
  int i = blockIdx.x * 4 + wave;
  if (i >= N_NODES) return;
  int beg = start[i], end = beg + deg[i];
  float a0[8], a1[8], s0, s1;
  attn_node_dual(buf, 0, 384, i, li, g, beg, end, csr, a0, a1, s0, s1);
  if (g != 0) return;
  float inv0 = 0.25f / (s0 + 1e-16f), inv1 = 0.25f / (s1 + 1e-16f);
  float* sp = S2 + (size_t)i * CH + li * 8;
  if (first) {
    float sk[8];
    unpack8(*(const uint4*)(buf + (size_t)i * 1024 + 768 + li * 8), sk);
#pragma unroll
    for (int c = 0; c < 8; ++c) sp[c] = sk[c] + a0[c] * inv0 + a1[c] * inv1;
  } else {
#pragma unroll
    for (int c = 0; c < 8; ++c) sp[c] += a0[c] * inv0 + a1[c] * inv1;
  }
}

// ---------------------------------------------------------------------------
// Fused pool (segment loop, no atomics — batch is sorted) + ELU + classifier
// + log_softmax. One block of 256 per graph: 2 rows x 128 ch.
// ---------------------------------------------------------------------------
__global__ __launch_bounds__(256) void pool_cls(
    const float* __restrict__ S2, const int* __restrict__ gstart,
    const int* __restrict__ gend, const float* __restrict__ Wfc,
    const float* __restrict__ bfc, float* __restrict__ out) {
  int g = blockIdx.x;
  int t = threadIdx.x;
  int c = t & (CH - 1), rr = t >> 7;
  int s0 = gstart[g], e0 = gend[g];
  float sum = 0.f;
  for (int i = s0 + rr; i < e0; i += 2) {
    float v = S2[(size_t)i * CH + c];
    v = v > 0.f ? v : expm1f(v);
    sum += v;
  }
  __shared__ float sh[256];
  __shared__ float p[CH];
  __shared__ float red[CH];
  __shared__ float logits[NCLS];
  sh[t] = sum;
  __syncthreads();
  if (t < CH) {
    float cnt = fmaxf((float)(e0 - s0), 1.f);
    p[t] = (sh[t] + sh[t + CH]) / cnt;
  }
  for (int cc = 0; cc < NCLS; ++cc) {
    __syncthreads();
    if (t < CH) red[t] = p[t] * Wfc[t * NCLS + cc];
    __syncthreads();
    for (int off = 64; off > 0; off >>= 1) {
      if (t < off) red[t] += red[t + off];
      __syncthreads();
    }
    if (t == 0) logits[cc] = red[0] + bfc[cc];
  }
  __syncthreads();
  if (t == 0) {
    float mx = -INFINITY;
    for (int cc = 0; cc < NCLS; ++cc) mx = fmaxf(mx, logits[cc]);
    float se = 0.f;
    for (int cc = 0; cc < NCLS; ++cc) se += expf(logits[cc] - mx);
    float ls = mx + logf(se);
    for (int cc = 0; cc < NCLS; ++cc) out[g * NCLS + cc] = logits[cc] - ls;
  }
}

// ---------------------------------------------------------------------------
extern "C" void kernel_launch(void* const* d_in, const int* in_sizes, int n_in,
                              void* d_out, int out_size, void* d_ws, size_t ws_size,
                              hipStream_t stream) {
  const float* x    = (const float*)d_in[0];
  const int*   ei   = (const int*)d_in[1];
  const int*   batch= (const int*)d_in[2];
  const float* Wq1 = (const float*)d_in[3];  const float* bq1 = (const float*)d_in[4];
  const float* Wk1 = (const float*)d_in[5];  const float* bk1 = (const float*)d_in[6];
  const float* Wv1 = (const float*)d_in[7];  const float* bv1 = (const float*)d_in[8];
  const float* Ws1 = (const float*)d_in[9];  const float* bs1 = (const float*)d_in[10];
  const float* Wq2 = (const float*)d_in[11]; const float* bq2 = (const float*)d_in[12];
  const float* Wk2 = (const float*)d_in[13]; const float* bk2 = (const float*)d_in[14];
  const float* Wv2 = (const float*)d_in[15]; const float* bv2 = (const float*)d_in[16];
  const float* Ws2 = (const float*)d_in[17]; const float* bs2 = (const float*)d_in[18];
  const float* Wfc = (const float*)d_in[19]; const float* bfc = (const float*)d_in[20];
  float* out = (float*)d_out;

  // Workspace (~183 MB). S2 (fp32 N*128 = 25.6MB) aliases xb (dead after L1 GEMMs).
  ushort_t* xb   = (ushort_t*)d_ws;                    // N x 256 bf16
  float*    S2   = (float*)d_ws;                       // N x 128 fp32 (aliases xb)
  ushort_t* BIG  = xb + (size_t)N_NODES * FEAT;        // N x 1024 bf16
  ushort_t* H1b  = BIG + (size_t)N_NODES * 1024;       // N x 512 bf16
  ushort_t* W1t  = H1b + (size_t)N_NODES * HID;        // 2048*256
  float*    Bh1  = (float*)(W1t + L1_W);               // 2048
  ushort_t* W2t  = (ushort_t*)(Bh1 + 2048);            // 1664*512
  float*    Bh2  = (float*)(W2t + L2_W);               // 1664
  int* deg    = (int*)(Bh2 + 1664);
  int* start  = deg + N_NODES;
  int* cursor = start + N_NODES;
  int* csr    = cursor + N_NODES;
  int* gstart = csr + EDGES;
  int* gend   = gstart + NGRAPH;
  int* counter= gend + NGRAPH;

  const int* srcp = ei;
  const int* dstp = ei + EDGES;

  // ---- prep ----
  cvt_bf16_kernel<<<(N_NODES * FEAT / 4 + 255) / 256, 256, 0, stream>>>(x, xb, N_NODES * FEAT / 4);
  prep_tp<<<T1 + T2, 256, 0, stream>>>(Wq1, Wk1, Wv1, Ws1, Wq2, Wk2, Wv2, Ws2, W1t, W2t);
  bias_kernel<<<(2048 + 1664 + 255) / 256, 256, 0, stream>>>(
      bq1, bk1, bv1, bs1, bq2, bk2, bv2, bs2, Bh1, Bh2);

  // ---- CSR build ----
  zero_kernel<<<(N_NODES + 255) / 256, 256, 0, stream>>>(deg, counter, gstart, gend);
  hist_bounds_kernel<<<(EDGES + 255) / 256, 256, 0, stream>>>(dstp, deg, batch, gstart, gend);
  alloc_kernel<<<(N_NODES + 255) / 256, 256, 0, stream>>>(deg, counter, start, cursor);
  scatter_kernel<<<(EDGES + 255) / 256, 256, 0, stream>>>(srcp, dstp, cursor, csr);

  const int gx8 = 49 * 8;               // 392 row tiles (padded; kernel guards)
  const int ga = (N_NODES + 3) / 4;     // 12500

  // ---- layer 1: per head-pair, GEMM (1024 cols) + per-head attention ----
  for (int p = 0; p < 2; ++p) {
    gemm_bt<<<gx8 * 8, 256, 0, stream>>>(
        xb, W1t + (size_t)p * 1024 * FEAT, Bh1 + p * 1024, BIG, 1024, N_NODES, FEAT, 8);
    attn1_kernel<<<dim3(ga, 2), 256, 0, stream>>>(BIG, start, deg, csr, H1b, p);
  }

  // ---- layer 2: pair0 GEMM includes skip cols (896, ldc=1024) ----
  gemm_bt<<<gx8 * 7, 256, 0, stream>>>(
      H1b, W2t, Bh2, BIG, 1024, N_NODES, HID, 7);
  attn2_kernel<<<ga, 256, 0, stream>>>(BIG, start, deg, csr, S2, 1);
  gemm_bt<<<gx8 * 6, 256, 0, stream>>>(
      H1b, W2t + (size_t)896 * HID, Bh2 + 896, BIG, 1024, N_NODES, HID, 6);
  attn2_kernel<<<ga, 256, 0, stream>>>(BIG, start, deg, csr, S2, 0);

  // ---- fused pool + classify ----
  pool_cls<<<NGRAPH, 256, 0, stream>>>(S2, gstart, gend, Wfc, bfc, out);
}

// Round 10
// 632.857 us; speedup vs baseline: 1.0888x; 1.0664x over previous
//
#include <hip/hip_runtime.h>
#include <math.h>
#include <stdint.h>

#define N_NODES 50000
#define FEAT    256
#define EDGES   200000
#define HEADS   4
#define CH      128
#define HID     512   // HEADS*CH
#define NGRAPH  256
#define NCLS    10

typedef unsigned short ushort_t;
typedef unsigned int uint_t;
typedef __attribute__((ext_vector_type(8))) short bf16x8;
typedef __attribute__((ext_vector_type(4))) float f32x4;

__device__ __forceinline__ ushort_t f2bf(float f) {  // round-to-nearest-even
  uint_t u = __float_as_uint(f);
  u += 0x7FFF + ((u >> 16) & 1);
  return (ushort_t)(u >> 16);
}
__device__ __forceinline__ float bf2f(ushort_t h) {
  return __uint_as_float(((uint_t)h) << 16);
}
__device__ __forceinline__ void unpack8(uint4 w, float* f) {
  f[0] = bf2f((ushort_t)w.x); f[1] = bf2f((ushort_t)(w.x >> 16));
  f[2] = bf2f((ushort_t)w.y); f[3] = bf2f((ushort_t)(w.y >> 16));
  f[4] = bf2f((ushort_t)w.z); f[5] = bf2f((ushort_t)(w.z >> 16));
  f[6] = bf2f((ushort_t)w.w); f[7] = bf2f((ushort_t)(w.w >> 16));
}

// ---------------------------------------------------------------------------
// bf16 MFMA GEMM: C[M,N] = A[M,K] @ Bt[N,K]^T + bias (bf16 out)
// 128x128 tile, BK=32, 16 KB LDS. XCD-swizzled 1-D grid (round-7: FETCH
// 180->34 MB). Fragment swizzle (r>>1)&3 and epilogue swizzle rq<<4 are
// 2-way max (round-8: SQ_LDS_BANK_CONFLICT == 0). Do not touch.
// ---------------------------------------------------------------------------
__global__ __launch_bounds__(256) void gemm_bt(
    const ushort_t* __restrict__ A, const ushort_t* __restrict__ Bt,
    const float* __restrict__ bias, ushort_t* __restrict__ C, int ldc,
    int M, int K, int ncol) {
  __shared__ __align__(16) ushort_t smem[8192];   // 16 KB total
  ushort_t* sA = smem;                            // 128 x 32
  ushort_t* sB = smem + 4096;                     // 128 x 32
  const int tid = threadIdx.x;
  const int lane = tid & 63, wave = tid >> 6;
  const int wr = wave >> 1, wc = wave & 1;

  // XCD-aware decode: rt = grp*8 + (b%8), c = (b/8)%ncol
  int b = blockIdx.x;
  int per = ncol << 3;
  int grp = b / per;
  int rem = b - grp * per;
  int rloc = rem & 7;
  int c = rem >> 3;
  const int rowBase = (grp * 8 + rloc) * 128;
  const int colBase = c * 128;
  if (rowBase >= M) return;

  f32x4 acc[4][4] = {};

  for (int k0 = 0; k0 < K; k0 += 32) {
#pragma unroll
    for (int l = 0; l < 2; ++l) {
      int slot = l * 256 + tid;           // 0..511
      int rl = slot >> 2;                 // row/col 0..127
      int pos = slot & 3;                 // stored chunk slot
      int cg = pos ^ ((rl >> 1) & 3);     // swizzled global chunk
      {
        int row = rowBase + rl;
        row = row < M ? row : M - 1;      // clamp tail (epilogue guards)
        const ushort_t* gp = A + (size_t)row * K + k0 + cg * 8;
        __builtin_amdgcn_global_load_lds(
            (const __attribute__((address_space(1))) uint_t*)gp,
            (__attribute__((address_space(3))) uint_t*)(sA + slot * 8),
            16, 0, 0);
      }
      {
        int n = colBase + rl;
        const ushort_t* gp = Bt + (size_t)n * K + k0 + cg * 8;
        __builtin_amdgcn_global_load_lds(
            (const __attribute__((address_space(1))) uint_t*)gp,
            (__attribute__((address_space(3))) uint_t*)(sB + slot * 8),
            16, 0, 0);
      }
    }
    __syncthreads();
    const int fr = lane & 15, c0 = lane >> 4;
    bf16x8 af[4], bfr[4];
#pragma unroll
    for (int i = 0; i < 4; ++i) {
      int r = wr * 64 + i * 16 + fr;
      af[i] = *(const bf16x8*)(sA + r * 32 + ((c0 ^ ((r >> 1) & 3)) * 8));
      int n = wc * 64 + i * 16 + fr;
      bfr[i] = *(const bf16x8*)(sB + n * 32 + ((c0 ^ ((n >> 1) & 3)) * 8));
    }
#pragma unroll
    for (int i = 0; i < 4; ++i)
#pragma unroll
      for (int j = 0; j < 4; ++j)
        acc[i][j] = __builtin_amdgcn_mfma_f32_16x16x32_bf16(af[i], bfr[j], acc[i][j], 0, 0, 0);
    __syncthreads();
  }

  // Epilogue: per-wave LDS repack in two 32-row halves (4 KB/wave region).
  // C/D layout col=lane&15, row=(lane>>4)*4+reg (m89-verified).
  ushort_t* wbuf = smem + wave * 2048;    // 32 x 64 bf16
  const int rq = lane >> 4, fc = lane & 15;
  float bv[4];
#pragma unroll
  for (int j = 0; j < 4; ++j) bv[j] = bias[colBase + wc * 64 + j * 16 + fc];
#pragma unroll
  for (int h = 0; h < 2; ++h) {
#pragma unroll
    for (int ii = 0; ii < 2; ++ii) {
      int i = h * 2 + ii;
#pragma unroll
      for (int j = 0; j < 4; ++j)
#pragma unroll
        for (int r = 0; r < 4; ++r) {
          int rl = ii * 16 + rq * 4 + r;          // 0..31 ; (rl>>2)&3 == rq
          int cl = j * 16 + fc;                   // 0..63
          int cs = cl ^ (rq << 4);                // rq -> bank octet
          wbuf[rl * 64 + cs] = f2bf(acc[i][j][r] + bv[j]);
        }
    }
    // read back: lanes 0..7 cover all 32 banks (ci*4); remap chunk by rq
    int ci = lane & 7;
    int rbase = lane >> 3;                         // 0..7
#pragma unroll
    for (int rg = 0; rg < 4; ++rg) {
      int rr = rg * 8 + rbase;                     // 0..31
      int rowg = rowBase + wr * 64 + h * 32 + rr;
      int cg = ci ^ (((rr >> 2) & 3) << 1);
      uint4 val = *(const uint4*)(wbuf + rr * 64 + (ci << 3));
      if (rowg < M)
        *(uint4*)(C + (size_t)rowg * ldc + colBase + wc * 64 + cg * 8) = val;
    }
  }
}

// ---------------------------------------------------------------------------
// Prep: x -> bf16; weights -> transposed bf16 via 32x32 LDS tile transpose.
// W1t[2048][256]: n -> p=n>>10, hh=(n>>9)&1, sel=(n>>7)&3 (q,k,v,s),
//                 c=(2p+hh)*128+(n&127)
// W2t[1664][512]: n<768: heads 0,1 (q|k|v per 128); [768,896): skip (Ws2);
//                 n>=896: heads 2,3.
// ---------------------------------------------------------------------------
__global__ void cvt_bf16_kernel(const float* __restrict__ in, ushort_t* __restrict__ out, int n4) {
  int i = blockIdx.x * blockDim.x + threadIdx.x;
  if (i >= n4) return;
  float4 f = *(const float4*)(in + (size_t)i * 4);
  uint_t lo = (uint_t)f2bf(f.x) | ((uint_t)f2bf(f.y) << 16);
  uint_t hi = (uint_t)f2bf(f.z) | ((uint_t)f2bf(f.w) << 16);
  ((uint2*)out)[i] = make_uint2(lo, hi);
}

#define L1_W   (2048 * FEAT)
#define L2_W   (1664 * HID)
#define T1     512   // (2048/32)*(256/32)
#define T2     832   // (1664/32)*(512/32)

__global__ __launch_bounds__(256) void prep_tp(
    const float* __restrict__ Wq1, const float* __restrict__ Wk1,
    const float* __restrict__ Wv1, const float* __restrict__ Ws1,
    const float* __restrict__ Wq2, const float* __restrict__ Wk2,
    const float* __restrict__ Wv2, const float* __restrict__ Ws2,
    ushort_t* __restrict__ W1t, ushort_t* __restrict__ W2t) {
  __shared__ float tile[32][33];
  int t = blockIdx.x;
  const float* W; int ldw, c0, n0, k0, ldk; ushort_t* dst;
  if (t < T1) {
    int nb = t >> 3, kb = t & 7;
    n0 = nb * 32; k0 = kb * 32; ldk = FEAT; dst = W1t;
    int p = n0 >> 10, n1 = n0 & 1023, hh = n1 >> 9, sel = (n1 >> 7) & 3;
    c0 = (2 * p + hh) * CH + (n1 & (CH - 1));
    W = sel == 0 ? Wq1 : sel == 1 ? Wk1 : sel == 2 ? Wv1 : Ws1;
    ldw = HID;
  } else {
    t -= T1;
    int nb = t >> 4, kb = t & 15;
    n0 = nb * 32; k0 = kb * 32; ldk = HID; dst = W2t;
    if (n0 < 768 || n0 >= 896) {
      int n2 = (n0 < 768) ? n0 : n0 - 896;
      int hb = (n0 < 768) ? 0 : 2;
      int hh = hb + n2 / 384, r = n2 % 384, sel = r >> 7;
      c0 = hh * CH + (r & (CH - 1));
      W = sel == 0 ? Wq2 : sel == 1 ? Wk2 : Wv2;
      ldw = HID;
    } else {
      c0 = n0 - 768; W = Ws2; ldw = CH;
    }
  }
  int col = threadIdx.x & 31, rw = threadIdx.x >> 5;
#pragma unroll
  for (int ph = 0; ph < 4; ++ph) {
    int kk = rw + ph * 8;
    tile[kk][col] = W[(size_t)(k0 + kk) * ldw + c0 + col];   // coalesced read
  }
  __syncthreads();
#pragma unroll
  for (int ph = 0; ph < 4; ++ph) {
    int dn = rw + ph * 8;
    dst[(size_t)(n0 + dn) * ldk + k0 + col] = f2bf(tile[col][dn]);  // coalesced write
  }
}

__global__ void bias_kernel(
    const float* __restrict__ bq1, const float* __restrict__ bk1,
    const float* __restrict__ bv1, const float* __restrict__ bs1,
    const float* __restrict__ bq2, const float* __restrict__ bk2,
    const float* __restrict__ bv2, const float* __restrict__ bs2,
    float* __restrict__ Bh1, float* __restrict__ Bh2) {
  int n = blockIdx.x * blockDim.x + threadIdx.x;
  if (n < 2048) {
    int p = n >> 10, n1 = n & 1023, hh = n1 >> 9, sel = (n1 >> 7) & 3;
    int c = (2 * p + hh) * CH + (n1 & (CH - 1));
    const float* b = sel == 0 ? bq1 : sel == 1 ? bk1 : sel == 2 ? bv1 : bs1;
    Bh1[n] = b[c];
  } else {
    int n2 = n - 2048;
    if (n2 >= 1664) return;
    if (n2 < 768 || n2 >= 896) {
      int nn = (n2 < 768) ? n2 : n2 - 896;
      int hb = (n2 < 768) ? 0 : 2;
      int hh = hb + nn / 384, r = nn % 384, sel = r >> 7;
      int c = hh * CH + (r & (CH - 1));
      const float* b = sel == 0 ? bq2 : sel == 1 ? bk2 : bv2;
      Bh2[n2] = b[c];
    } else {
      Bh2[n2] = bs2[n2 - 768];
    }
  }
}

// ---------------------------------------------------------------------------
// CSR build: zero -> hist+bounds -> alloc (wave atomic) -> scatter
// ---------------------------------------------------------------------------
__global__ void zero_kernel(int* __restrict__ deg, int* __restrict__ counter,
                            int* __restrict__ gstart, int* __restrict__ gend) {
  int i = blockIdx.x * blockDim.x + threadIdx.x;
  if (i < N_NODES) deg[i] = 0;
  if (i < NGRAPH) { gstart[i] = 0; gend[i] = 0; }
  if (i == 0) counter[0] = 0;
}

__global__ void hist_bounds_kernel(const int* __restrict__ dst, int* __restrict__ deg,
                                   const int* __restrict__ batch,
                                   int* __restrict__ gstart, int* __restrict__ gend) {
  int t = blockIdx.x * blockDim.x + threadIdx.x;
  if (t < EDGES) atomicAdd(&deg[dst[t]], 1);
  if (t < N_NODES) {
    int b = batch[t];
    if (t == 0 || batch[t - 1] != b) gstart[b] = t;
    if (t == N_NODES - 1 || batch[t + 1] != b) gend[b] = t + 1;
  }
}

__global__ void alloc_kernel(const int* __restrict__ deg, int* __restrict__ counter,
                             int* __restrict__ start, int* __restrict__ cursor) {
  int i = blockIdx.x * blockDim.x + threadIdx.x;
  int lane = threadIdx.x & 63;
  int v = (i < N_NODES) ? deg[i] : 0;
  int sum = v;
#pragma unroll
  for (int off = 1; off < 64; off <<= 1) {
    int t = __shfl_up(sum, off);
    if (lane >= off) sum += t;
  }
  int excl = sum - v;
  int waveTot = __shfl(sum, 63);
  int base = 0;
  if (lane == 63) base = atomicAdd(counter, waveTot);
  base = __shfl(base, 63);
  if (i < N_NODES) {
    start[i] = base + excl;
    cursor[i] = base + excl;
  }
}

__global__ void scatter_kernel(const int* __restrict__ src, const int* __restrict__ dst,
                               int* __restrict__ cursor, int* __restrict__ csr) {
  int e = blockIdx.x * blockDim.x + threadIdx.x;
  if (e < EDGES) {
    int pos = atomicAdd(&cursor[dst[e]], 1);
    csr[pos] = src[e];
  }
}

// ---------------------------------------------------------------------------
// Attention cores. VALU-bound (round-8: VALUBusy ~107%); this version drops
// online-max tracking entirely: alpha = q.k/sqrt(128) is bounded by
// |q||k|/11.3 ~ O(10) even fully-aligned, so exp() cannot overflow fp32 and
// softmax is shift-invariant -> plain sum-of-exp is exact. Also __expf
// (v_exp_f32, ~2 insts) instead of libm expf (~12). Group merge is pure adds.
// attn1: one wave per (node, head). attn2: one wave per node, dual-head.
// 4 x 16-lane groups process 4 edges in parallel.
// ---------------------------------------------------------------------------
#define INV_SQRT_CH 0.08838834764831845f

__device__ __forceinline__ void attn_node_head(
    const ushort_t* __restrict__ buf, int off,
    int i, int li, int g, int beg, int end, const int* __restrict__ csr,
    float* a, float& sout) {
  float q[8];
  unpack8(*(const uint4*)(buf + (size_t)i * 1024 + off + li * 8), q);
  float s = 0.f;
#pragma unroll
  for (int c = 0; c < 8; ++c) a[c] = 0.f;
  for (int e0 = beg; e0 < end; e0 += 4) {
    int eg = e0 + g;
    bool valid = eg < end;
    int j = csr[valid ? eg : beg];
    const ushort_t* jp = buf + (size_t)j * 1024 + off;
    uint4 kw = *(const uint4*)(jp + CH + li * 8);
    uint4 vw = *(const uint4*)(jp + 2 * CH + li * 8);
    float kf[8]; unpack8(kw, kf);
    float p = q[0]*kf[0]+q[1]*kf[1]+q[2]*kf[2]+q[3]*kf[3]+
              q[4]*kf[4]+q[5]*kf[5]+q[6]*kf[6]+q[7]*kf[7];
    p += __shfl_xor(p, 1);
    p += __shfl_xor(p, 2);
    p += __shfl_xor(p, 4);
    p += __shfl_xor(p, 8);
    float w = valid ? __expf(p * INV_SQRT_CH) : 0.f;
    float vf[8]; unpack8(vw, vf);
    s += w;
#pragma unroll
    for (int c = 0; c < 8; ++c) a[c] = fmaf(w, vf[c], a[c]);
  }
#pragma unroll
  for (int ox = 16; ox <= 32; ox <<= 1) {
    s += __shfl_xor(s, ox);
#pragma unroll
    for (int c = 0; c < 8; ++c) a[c] += __shfl_xor(a[c], ox);
  }
  sout = s;
}

__device__ __forceinline__ void attn_node_dual(
    const ushort_t* __restrict__ buf, int qo0, int qo1,
    int i, int li, int g, int beg, int end, const int* __restrict__ csr,
    float* a0, float* a1, float& s0o, float& s1o) {
  const ushort_t* ip = buf + (size_t)i * 1024;
  float q0[8], q1[8];
  unpack8(*(const uint4*)(ip + qo0 + li * 8), q0);
  unpack8(*(const uint4*)(ip + qo1 + li * 8), q1);
  float s0 = 0.f, s1 = 0.f;
#pragma unroll
  for (int c = 0; c < 8; ++c) { a0[c] = 0.f; a1[c] = 0.f; }
  for (int e0 = beg; e0 < end; e0 += 4) {
    int eg = e0 + g;
    bool valid = eg < end;
    int j = csr[valid ? eg : beg];
    const ushort_t* jp = buf + (size_t)j * 1024;
    uint4 kw0 = *(const uint4*)(jp + qo0 + CH + li * 8);
    uint4 vw0 = *(const uint4*)(jp + qo0 + 2 * CH + li * 8);
    uint4 kw1 = *(const uint4*)(jp + qo1 + CH + li * 8);
    uint4 vw1 = *(const uint4*)(jp + qo1 + 2 * CH + li * 8);
    float kf[8];
    unpack8(kw0, kf);
    float p0 = q0[0]*kf[0]+q0[1]*kf[1]+q0[2]*kf[2]+q0[3]*kf[3]+
               q0[4]*kf[4]+q0[5]*kf[5]+q0[6]*kf[6]+q0[7]*kf[7];
    unpack8(kw1, kf);
    float p1 = q1[0]*kf[0]+q1[1]*kf[1]+q1[2]*kf[2]+q1[3]*kf[3]+
               q1[4]*kf[4]+q1[5]*kf[5]+q1[6]*kf[6]+q1[7]*kf[7];
#pragma unroll
    for (int ox = 1; ox <= 8; ox <<= 1) {
      p0 += __shfl_xor(p0, ox);
      p1 += __shfl_xor(p1, ox);
    }
    float w0 = valid ? __expf(p0 * INV_SQRT_CH) : 0.f;
    float w1 = valid ? __expf(p1 * INV_SQRT_CH) : 0.f;
    float vf[8];
    unpack8(vw0, vf);
    s0 += w0;
#pragma unroll
    for (int c = 0; c < 8; ++c) a0[c] = fmaf(w0, vf[c], a0[c]);
    unpack8(vw1, vf);
    s1 += w1;
#pragma unroll
    for (int c = 0; c < 8; ++c) a1[c] = fmaf(w1, vf[c], a1[c]);
  }
#pragma unroll
  for (int ox = 16; ox <= 32; ox <<= 1) {
    s0 += __shfl_xor(s0, ox);
    s1 += __shfl_xor(s1, ox);
#pragma unroll
    for (int c = 0; c < 8; ++c) {
      a0[c] += __shfl_xor(a0[c], ox);
      a1[c] += __shfl_xor(a1[c], ox);
    }
  }
  s0o = s0; s1o = s1;
}

// layer 1 (pair p, hh = blockIdx.y): layout [q|k|v|s] x 2 heads, stride 1024.
// One wave per (node, head). Fused skip-add + ELU; writes H1b col (2p+hh)*128.
__global__ __launch_bounds__(256) void attn1_kernel(
    const ushort_t* __restrict__ QKVS2, const int* __restrict__ start,
    const int* __restrict__ deg, const int* __restrict__ csr,
    ushort_t* __restrict__ H1b, int p) {
  int wave = threadIdx.x >> 6, lane = threadIdx.x & 63;
  int li = lane & 15, g = lane >> 4;
  int i = blockIdx.x * 4 + wave;
  if (i >= N_NODES) return;
  int hh = blockIdx.y;
  int beg = start[i], end = beg + deg[i];
  float a[8], s;
  attn_node_head(QKVS2, hh * 512, i, li, g, beg, end, csr, a, s);
  if (g != 0) return;
  float inv = 1.f / (s + 1e-16f);
  float sk[8];
  unpack8(*(const uint4*)(QKVS2 + (size_t)i * 1024 + hh * 512 + 384 + li * 8), sk);
  uint4 ow;
  uint_t* op = (uint_t*)&ow;
#pragma unroll
  for (int c = 0; c < 4; ++c) {
    float o0 = a[2 * c] * inv + sk[2 * c];
    float o1 = a[2 * c + 1] * inv + sk[2 * c + 1];
    o0 = o0 > 0.f ? o0 : expm1f(o0);
    o1 = o1 > 0.f ? o1 : expm1f(o1);
    op[c] = (uint_t)f2bf(o0) | ((uint_t)f2bf(o1) << 16);
  }
  *(uint4*)(H1b + (size_t)i * HID + (2 * p + hh) * CH + li * 8) = ow;
}

// layer 2: layout [q0|k0|v0 | q1|k1|v1 | skip], stride 1024. Dual-head.
// first=1: S2 = skip + 0.25*(m0+m1); else S2 += 0.25*(m0+m1).
__global__ __launch_bounds__(256) void attn2_kernel(
    const ushort_t* __restrict__ buf, const int* __restrict__ start,
    const int* __restrict__ deg, const int* __restrict__ csr,
    float* __restrict__ S2, int first) {
  int wave = threadIdx.x >> 6, lane = threadIdx.x & 63;
  int li = lane & 15, g = lane >> 4;
  int i = blockIdx.x * 4 + wave;
  if (i >= N_NODES) return;
  int beg = start[i], end = beg + deg[i];
  float a0[8], a1[8], s0, s1;
  attn_node_dual(buf, 0, 384, i, li, g, beg, end, csr, a0, a1, s0, s1);
  if (g != 0) return;
  float inv0 = 0.25f / (s0 + 1e-16f), inv1 = 0.25f / (s1 + 1e-16f);
  float* sp = S2 + (size_t)i * CH + li * 8;
  if (first) {
    float sk[8];
    unpack8(*(const uint4*)(buf + (size_t)i * 1024 + 768 + li * 8), sk);
#pragma unroll
    for (int c = 0; c < 8; ++c) sp[c] = sk[c] + a0[c] * inv0 + a1[c] * inv1;
  } else {
#pragma unroll
    for (int c = 0; c < 8; ++c) sp[c] += a0[c] * inv0 + a1[c] * inv1;
  }
}

// ---------------------------------------------------------------------------
// Fused pool (segment loop, no atomics — batch is sorted) + ELU + classifier
// + log_softmax. One block of 256 per graph: 2 rows x 128 ch.
// ---------------------------------------------------------------------------
__global__ __launch_bounds__(256) void pool_cls(
    const float* __restrict__ S2, const int* __restrict__ gstart,
    const int* __restrict__ gend, const float* __restrict__ Wfc,
    const float* __restrict__ bfc, float* __restrict__ out) {
  int g = blockIdx.x;
  int t = threadIdx.x;
  int c = t & (CH - 1), rr = t >> 7;
  int s0 = gstart[g], e0 = gend[g];
  float sum = 0.f;
  for (int i = s0 + rr; i < e0; i += 2) {
    float v = S2[(size_t)i * CH + c];
    v = v > 0.f ? v : expm1f(v);
    sum += v;
  }
  __shared__ float sh[256];
  __shared__ float p[CH];
  __shared__ float red[CH];
  __shared__ float logits[NCLS];
  sh[t] = sum;
  __syncthreads();
  if (t < CH) {
    float cnt = fmaxf((float)(e0 - s0), 1.f);
    p[t] = (sh[t] + sh[t + CH]) / cnt;
  }
  for (int cc = 0; cc < NCLS; ++cc) {
    __syncthreads();
    if (t < CH) red[t] = p[t] * Wfc[t * NCLS + cc];
    __syncthreads();
    for (int off = 64; off > 0; off >>= 1) {
      if (t < off) red[t] += red[t + off];
      __syncthreads();
    }
    if (t == 0) logits[cc] = red[0] + bfc[cc];
  }
  __syncthreads();
  if (t == 0) {
    float mx = -INFINITY;
    for (int cc = 0; cc < NCLS; ++cc) mx = fmaxf(mx, logits[cc]);
    float se = 0.f;
    for (int cc = 0; cc < NCLS; ++cc) se += expf(logits[cc] - mx);
    float ls = mx + logf(se);
    for (int cc = 0; cc < NCLS; ++cc) out[g * NCLS + cc] = logits[cc] - ls;
  }
}

// ---------------------------------------------------------------------------
extern "C" void kernel_launch(void* const* d_in, const int* in_sizes, int n_in,
                              void* d_out, int out_size, void* d_ws, size_t ws_size,
                              hipStream_t stream) {
  const float* x    = (const float*)d_in[0];
  const int*   ei   = (const int*)d_in[1];
  const int*   batch= (const int*)d_in[2];
  const float* Wq1 = (const float*)d_in[3];  const float* bq1 = (const float*)d_in[4];
  const float* Wk1 = (const float*)d_in[5];  const float* bk1 = (const float*)d_in[6];
  const float* Wv1 = (const float*)d_in[7];  const float* bv1 = (const float*)d_in[8];
  const float* Ws1 = (const float*)d_in[9];  const float* bs1 = (const float*)d_in[10];
  const float* Wq2 = (const float*)d_in[11]; const float* bq2 = (const float*)d_in[12];
  const float* Wk2 = (const float*)d_in[13]; const float* bk2 = (const float*)d_in[14];
  const float* Wv2 = (const float*)d_in[15]; const float* bv2 = (const float*)d_in[16];
  const float* Ws2 = (const float*)d_in[17]; const float* bs2 = (const float*)d_in[18];
  const float* Wfc = (const float*)d_in[19]; const float* bfc = (const float*)d_in[20];
  float* out = (float*)d_out;

  // Workspace (~183 MB). S2 (fp32 N*128 = 25.6MB) aliases xb (dead after L1 GEMMs).
  ushort_t* xb   = (ushort_t*)d_ws;                    // N x 256 bf16
  float*    S2   = (float*)d_ws;                       // N x 128 fp32 (aliases xb)
  ushort_t* BIG  = xb + (size_t)N_NODES * FEAT;        // N x 1024 bf16
  ushort_t* H1b  = BIG + (size_t)N_NODES * 1024;       // N x 512 bf16
  ushort_t* W1t  = H1b + (size_t)N_NODES * HID;        // 2048*256
  float*    Bh1  = (float*)(W1t + L1_W);               // 2048
  ushort_t* W2t  = (ushort_t*)(Bh1 + 2048);            // 1664*512
  float*    Bh2  = (float*)(W2t + L2_W);               // 1664
  int* deg    = (int*)(Bh2 + 1664);
  int* start  = deg + N_NODES;
  int* cursor = start + N_NODES;
  int* csr    = cursor + N_NODES;
  int* gstart = csr + EDGES;
  int* gend   = gstart + NGRAPH;
  int* counter= gend + NGRAPH;

  const int* srcp = ei;
  const int* dstp = ei + EDGES;

  // ---- prep ----
  cvt_bf16_kernel<<<(N_NODES * FEAT / 4 + 255) / 256, 256, 0, stream>>>(x, xb, N_NODES * FEAT / 4);
  prep_tp<<<T1 + T2, 256, 0, stream>>>(Wq1, Wk1, Wv1, Ws1, Wq2, Wk2, Wv2, Ws2, W1t, W2t);
  bias_kernel<<<(2048 + 1664 + 255) / 256, 256, 0, stream>>>(
      bq1, bk1, bv1, bs1, bq2, bk2, bv2, bs2, Bh1, Bh2);

  // ---- CSR build ----
  zero_kernel<<<(N_NODES + 255) / 256, 256, 0, stream>>>(deg, counter, gstart, gend);
  hist_bounds_kernel<<<(EDGES + 255) / 256, 256, 0, stream>>>(dstp, deg, batch, gstart, gend);
  alloc_kernel<<<(N_NODES + 255) / 256, 256, 0, stream>>>(deg, counter, start, cursor);
  scatter_kernel<<<(EDGES + 255) / 256, 256, 0, stream>>>(srcp, dstp, cursor, csr);

  const int gx8 = 49 * 8;               // 392 row tiles (padded; kernel guards)
  const int ga = (N_NODES + 3) / 4;     // 12500

  // ---- layer 1: per head-pair, GEMM (1024 cols) + per-head attention ----
  for (int p = 0; p < 2; ++p) {
    gemm_bt<<<gx8 * 8, 256, 0, stream>>>(
        xb, W1t + (size_t)p * 1024 * FEAT, Bh1 + p * 1024, BIG, 1024, N_NODES, FEAT, 8);
    attn1_kernel<<<dim3(ga, 2), 256, 0, stream>>>(BIG, start, deg, csr, H1b, p);
  }

  // ---- layer 2: pair0 GEMM includes skip cols (896, ldc=1024) ----
  gemm_bt<<<gx8 * 7, 256, 0, stream>>>(
      H1b, W2t, Bh2, BIG, 1024, N_NODES, HID, 7);
  attn2_kernel<<<ga, 256, 0, stream>>>(BIG, start, deg, csr, S2, 1);
  gemm_bt<<<gx8 * 6, 256, 0, stream>>>(
      H1b, W2t + (size_t)896 * HID, Bh2 + 896, BIG, 1024, N_NODES, HID, 6);
  attn2_kernel<<<ga, 256, 0, stream>>>(BIG, start, deg, csr, S2, 0);

  // ---- fused pool + classify ----
  pool_cls<<<NGRAPH, 256, 0, stream>>>(S2, gstart, gend, Wfc, bfc, out);
}

// Round 11
// 623.790 us; speedup vs baseline: 1.1047x; 1.0145x over previous
//
#include <hip/hip_runtime.h>
#include <math.h>
#include <stdint.h>

#define N_NODES 50000
#define FEAT    256
#define EDGES   200000
#define HEADS   4
#define CH      128
#define HID     512   // HEADS*CH
#define NGRAPH  256
#define NCLS    10

typedef unsigned short ushort_t;
typedef unsigned int uint_t;
typedef __attribute__((ext_vector_type(8))) short bf16x8;
typedef __attribute__((ext_vector_type(4))) float f32x4;
typedef __attribute__((ext_vector_type(2))) float f32x2;

__device__ __forceinline__ ushort_t f2bf(float f) {  // round-to-nearest-even
  uint_t u = __float_as_uint(f);
  u += 0x7FFF + ((u >> 16) & 1);
  return (ushort_t)(u >> 16);
}
__device__ __forceinline__ float bf2f(ushort_t h) {
  return __uint_as_float(((uint_t)h) << 16);
}
__device__ __forceinline__ void unpack8(uint4 w, float* f) {
  f[0] = bf2f((ushort_t)w.x); f[1] = bf2f((ushort_t)(w.x >> 16));
  f[2] = bf2f((ushort_t)w.y); f[3] = bf2f((ushort_t)(w.y >> 16));
  f[4] = bf2f((ushort_t)w.z); f[5] = bf2f((ushort_t)(w.z >> 16));
  f[6] = bf2f((ushort_t)w.w); f[7] = bf2f((ushort_t)(w.w >> 16));
}
// 8 x fp8(e4m3) -> 8 x f32 via v_cvt_pk_f32_fp8 (4 insts)
__device__ __forceinline__ void unpack8_fp8(uint2 w, float* f) {
  f32x2 a = __builtin_amdgcn_cvt_pk_f32_fp8((int)w.x, false);
  f32x2 b = __builtin_amdgcn_cvt_pk_f32_fp8((int)w.x, true);
  f32x2 c = __builtin_amdgcn_cvt_pk_f32_fp8((int)w.y, false);
  f32x2 d = __builtin_amdgcn_cvt_pk_f32_fp8((int)w.y, true);
  f[0] = a[0]; f[1] = a[1]; f[2] = b[0]; f[3] = b[1];
  f[4] = c[0]; f[5] = c[1]; f[6] = d[0]; f[7] = d[1];
}
__device__ __forceinline__ uint_t pack4_fp8(float f0, float f1, float f2, float f3) {
  int v = __builtin_amdgcn_cvt_pk_fp8_f32(f0, f1, 0, false);
  v = __builtin_amdgcn_cvt_pk_fp8_f32(f2, f3, v, true);
  return (uint_t)v;
}

// ---------------------------------------------------------------------------
// bf16 MFMA GEMM with mixed-precision blocked output.
// 128x128 tile, BK=32, 16 KB LDS. XCD-swizzled 1-D grid (round-7: FETCH
// 180->34 MB). Fragment swizzle (r>>1)&3 and epilogue swizzle rq<<4 are
// 2-way max (round-8: SQ_LDS_BANK_CONFLICT == 0). Do not touch those.
// Output rows are byte-addressed with per-128-col-block mapping:
//  mode 1 (L1 pair): row 1536 B, per head (768 B): q bf16 @0, s bf16 @256,
//                    k fp8 @512, v fp8 @640.  Weight col order is q,k,v,s.
//  mode 2 (L2):      row 1280 B, per head (512 B): q bf16 @0, k fp8 @256,
//                    v fp8 @384; skip bf16 @1024 (block n0 in [768,896)).
// fp8 conversion happens in the readback (same LDS pattern -> still 0-conflict).
// ---------------------------------------------------------------------------
__global__ __launch_bounds__(256) void gemm_bt(
    const ushort_t* __restrict__ A, const ushort_t* __restrict__ Bt,
    const float* __restrict__ bias, char* __restrict__ Cb,
    int M, int K, int ncol, int mode) {
  __shared__ __align__(16) ushort_t smem[8192];   // 16 KB total
  ushort_t* sA = smem;                            // 128 x 32
  ushort_t* sB = smem + 4096;                     // 128 x 32
  const int tid = threadIdx.x;
  const int lane = tid & 63, wave = tid >> 6;
  const int wr = wave >> 1, wc = wave & 1;

  // XCD-aware decode: rt = grp*8 + (b%8), c = (b/8)%ncol
  int b = blockIdx.x;
  int per = ncol << 3;
  int grp = b / per;
  int rem = b - grp * per;
  int rloc = rem & 7;
  int c = rem >> 3;
  const int rowBase = (grp * 8 + rloc) * 128;
  const int colBase = c * 128;
  if (rowBase >= M) return;

  f32x4 acc[4][4] = {};

  for (int k0 = 0; k0 < K; k0 += 32) {
#pragma unroll
    for (int l = 0; l < 2; ++l) {
      int slot = l * 256 + tid;           // 0..511
      int rl = slot >> 2;                 // row/col 0..127
      int pos = slot & 3;                 // stored chunk slot
      int cg = pos ^ ((rl >> 1) & 3);     // swizzled global chunk
      {
        int row = rowBase + rl;
        row = row < M ? row : M - 1;      // clamp tail (epilogue guards)
        const ushort_t* gp = A + (size_t)row * K + k0 + cg * 8;
        __builtin_amdgcn_global_load_lds(
            (const __attribute__((address_space(1))) uint_t*)gp,
            (__attribute__((address_space(3))) uint_t*)(sA + slot * 8),
            16, 0, 0);
      }
      {
        int n = colBase + rl;
        const ushort_t* gp = Bt + (size_t)n * K + k0 + cg * 8;
        __builtin_amdgcn_global_load_lds(
            (const __attribute__((address_space(1))) uint_t*)gp,
            (__attribute__((address_space(3))) uint_t*)(sB + slot * 8),
            16, 0, 0);
      }
    }
    __syncthreads();
    const int fr = lane & 15, c0 = lane >> 4;
    bf16x8 af[4], bfr[4];
#pragma unroll
    for (int i = 0; i < 4; ++i) {
      int r = wr * 64 + i * 16 + fr;
      af[i] = *(const bf16x8*)(sA + r * 32 + ((c0 ^ ((r >> 1) & 3)) * 8));
      int n = wc * 64 + i * 16 + fr;
      bfr[i] = *(const bf16x8*)(sB + n * 32 + ((c0 ^ ((n >> 1) & 3)) * 8));
    }
#pragma unroll
    for (int i = 0; i < 4; ++i)
#pragma unroll
      for (int j = 0; j < 4; ++j)
        acc[i][j] = __builtin_amdgcn_mfma_f32_16x16x32_bf16(af[i], bfr[j], acc[i][j], 0, 0, 0);
    __syncthreads();
  }

  // ---- output block -> (byte offset, dtype), wave-uniform ----
  int koff, rowStride, isfp8;
  if (mode == 1) {
    rowStride = 1536;
    int hh = colBase >> 9, sel = (colBase >> 7) & 3;      // q,k,v,s
    koff = hh * 768 + (sel == 0 ? 0 : sel == 3 ? 256 : sel == 1 ? 512 : 640);
    isfp8 = (sel == 1 || sel == 2);
  } else {
    rowStride = 1280;
    if (colBase < 768) {
      int hh = colBase / 384, r = colBase % 384, sel = r >> 7;  // q,k,v
      koff = hh * 512 + (sel == 0 ? 0 : sel == 1 ? 256 : 384);
      isfp8 = (sel >= 1);
    } else { koff = 1024; isfp8 = 0; }
  }

  // Epilogue: per-wave LDS repack in two 32-row halves (4 KB/wave region).
  // C/D layout col=lane&15, row=(lane>>4)*4+reg (m89-verified).
  ushort_t* wbuf = smem + wave * 2048;    // 32 x 64 bf16
  const int rq = lane >> 4, fc = lane & 15;
  float bv[4];
#pragma unroll
  for (int j = 0; j < 4; ++j) bv[j] = bias[colBase + wc * 64 + j * 16 + fc];
#pragma unroll
  for (int h = 0; h < 2; ++h) {
#pragma unroll
    for (int ii = 0; ii < 2; ++ii) {
      int i = h * 2 + ii;
#pragma unroll
      for (int j = 0; j < 4; ++j)
#pragma unroll
        for (int r = 0; r < 4; ++r) {
          int rl = ii * 16 + rq * 4 + r;          // 0..31 ; (rl>>2)&3 == rq
          int cl = j * 16 + fc;                   // 0..63
          int cs = cl ^ (rq << 4);                // rq -> bank octet
          wbuf[rl * 64 + cs] = f2bf(acc[i][j][r] + bv[j]);
        }
    }
    // read back: lanes 0..7 cover all 32 banks (ci*4); remap chunk by rq
    int ci = lane & 7;
    int rbase = lane >> 3;                         // 0..7
#pragma unroll
    for (int rg = 0; rg < 4; ++rg) {
      int rr = rg * 8 + rbase;                     // 0..31
      int rowg = rowBase + wr * 64 + h * 32 + rr;
      int cg = ci ^ (((rr >> 2) & 3) << 1);
      uint4 val = *(const uint4*)(wbuf + rr * 64 + (ci << 3));
      if (rowg < M) {
        char* dstRow = Cb + (size_t)rowg * rowStride + koff;
        if (!isfp8) {
          *(uint4*)(dstRow + (wc * 64 + cg * 8) * 2) = val;
        } else {
          float f[8];
          f[0] = bf2f((ushort_t)val.x); f[1] = bf2f((ushort_t)(val.x >> 16));
          f[2] = bf2f((ushort_t)val.y); f[3] = bf2f((ushort_t)(val.y >> 16));
          f[4] = bf2f((ushort_t)val.z); f[5] = bf2f((ushort_t)(val.z >> 16));
          f[6] = bf2f((ushort_t)val.w); f[7] = bf2f((ushort_t)(val.w >> 16));
          uint2 o;
          o.x = pack4_fp8(f[0], f[1], f[2], f[3]);
          o.y = pack4_fp8(f[4], f[5], f[6], f[7]);
          *(uint2*)(dstRow + wc * 64 + cg * 8) = o;
        }
      }
    }
  }
}

// ---------------------------------------------------------------------------
// Prep: x -> bf16; weights -> transposed bf16 via 32x32 LDS tile transpose.
// W1t[2048][256]: n -> p=n>>10, hh=(n>>9)&1, sel=(n>>7)&3 (q,k,v,s),
//                 c=(2p+hh)*128+(n&127)
// W2t[1664][512]: n<768: heads 0,1 (q|k|v per 128); [768,896): skip (Ws2);
//                 n>=896: heads 2,3.
// ---------------------------------------------------------------------------
__global__ void cvt_bf16_kernel(const float* __restrict__ in, ushort_t* __restrict__ out, int n4) {
  int i = blockIdx.x * blockDim.x + threadIdx.x;
  if (i >= n4) return;
  float4 f = *(const float4*)(in + (size_t)i * 4);
  uint_t lo = (uint_t)f2bf(f.x) | ((uint_t)f2bf(f.y) << 16);
  uint_t hi = (uint_t)f2bf(f.z) | ((uint_t)f2bf(f.w) << 16);
  ((uint2*)out)[i] = make_uint2(lo, hi);
}

#define L1_W   (2048 * FEAT)
#define L2_W   (1664 * HID)
#define T1     512   // (2048/32)*(256/32)
#define T2     832   // (1664/32)*(512/32)

__global__ __launch_bounds__(256) void prep_tp(
    const float* __restrict__ Wq1, const float* __restrict__ Wk1,
    const float* __restrict__ Wv1, const float* __restrict__ Ws1,
    const float* __restrict__ Wq2, const float* __restrict__ Wk2,
    const float* __restrict__ Wv2, const float* __restrict__ Ws2,
    ushort_t* __restrict__ W1t, ushort_t* __restrict__ W2t) {
  __shared__ float tile[32][33];
  int t = blockIdx.x;
  const float* W; int ldw, c0, n0, k0, ldk; ushort_t* dst;
  if (t < T1) {
    int nb = t >> 3, kb = t & 7;
    n0 = nb * 32; k0 = kb * 32; ldk = FEAT; dst = W1t;
    int p = n0 >> 10, n1 = n0 & 1023, hh = n1 >> 9, sel = (n1 >> 7) & 3;
    c0 = (2 * p + hh) * CH + (n1 & (CH - 1));
    W = sel == 0 ? Wq1 : sel == 1 ? Wk1 : sel == 2 ? Wv1 : Ws1;
    ldw = HID;
  } else {
    t -= T1;
    int nb = t >> 4, kb = t & 15;
    n0 = nb * 32; k0 = kb * 32; ldk = HID; dst = W2t;
    if (n0 < 768 || n0 >= 896) {
      int n2 = (n0 < 768) ? n0 : n0 - 896;
      int hb = (n0 < 768) ? 0 : 2;
      int hh = hb + n2 / 384, r = n2 % 384, sel = r >> 7;
      c0 = hh * CH + (r & (CH - 1));
      W = sel == 0 ? Wq2 : sel == 1 ? Wk2 : Wv2;
      ldw = HID;
    } else {
      c0 = n0 - 768; W = Ws2; ldw = CH;
    }
  }
  int col = threadIdx.x & 31, rw = threadIdx.x >> 5;
#pragma unroll
  for (int ph = 0; ph < 4; ++ph) {
    int kk = rw + ph * 8;
    tile[kk][col] = W[(size_t)(k0 + kk) * ldw + c0 + col];   // coalesced read
  }
  __syncthreads();
#pragma unroll
  for (int ph = 0; ph < 4; ++ph) {
    int dn = rw + ph * 8;
    dst[(size_t)(n0 + dn) * ldk + k0 + col] = f2bf(tile[col][dn]);  // coalesced write
  }
}

__global__ void bias_kernel(
    const float* __restrict__ bq1, const float* __restrict__ bk1,
    const float* __restrict__ bv1, const float* __restrict__ bs1,
    const float* __restrict__ bq2, const float* __restrict__ bk2,
    const float* __restrict__ bv2, const float* __restrict__ bs2,
    float* __restrict__ Bh1, float* __restrict__ Bh2) {
  int n = blockIdx.x * blockDim.x + threadIdx.x;
  if (n < 2048) {
    int p = n >> 10, n1 = n & 1023, hh = n1 >> 9, sel = (n1 >> 7) & 3;
    int c = (2 * p + hh) * CH + (n1 & (CH - 1));
    const float* b = sel == 0 ? bq1 : sel == 1 ? bk1 : sel == 2 ? bv1 : bs1;
    Bh1[n] = b[c];
  } else {
    int n2 = n - 2048;
    if (n2 >= 1664) return;
    if (n2 < 768 || n2 >= 896) {
      int nn = (n2 < 768) ? n2 : n2 - 896;
      int hb = (n2 < 768) ? 0 : 2;
      int hh = hb + nn / 384, r = nn % 384, sel = r >> 7;
      int c = hh * CH + (r & (CH - 1));
      const float* b = sel == 0 ? bq2 : sel == 1 ? bk2 : bv2;
      Bh2[n2] = b[c];
    } else {
      Bh2[n2] = bs2[n2 - 768];
    }
  }
}

// ---------------------------------------------------------------------------
// CSR build: zero -> hist+bounds -> alloc (wave atomic) -> scatter
// ---------------------------------------------------------------------------
__global__ void zero_kernel(int* __restrict__ deg, int* __restrict__ counter,
                            int* __restrict__ gstart, int* __restrict__ gend) {
  int i = blockIdx.x * blockDim.x + threadIdx.x;
  if (i < N_NODES) deg[i] = 0;
  if (i < NGRAPH) { gstart[i] = 0; gend[i] = 0; }
  if (i == 0) counter[0] = 0;
}

__global__ void hist_bounds_kernel(const int* __restrict__ dst, int* __restrict__ deg,
                                   const int* __restrict__ batch,
                                   int* __restrict__ gstart, int* __restrict__ gend) {
  int t = blockIdx.x * blockDim.x + threadIdx.x;
  if (t < EDGES) atomicAdd(&deg[dst[t]], 1);
  if (t < N_NODES) {
    int b = batch[t];
    if (t == 0 || batch[t - 1] != b) gstart[b] = t;
    if (t == N_NODES - 1 || batch[t + 1] != b) gend[b] = t + 1;
  }
}

__global__ void alloc_kernel(const int* __restrict__ deg, int* __restrict__ counter,
                             int* __restrict__ start, int* __restrict__ cursor) {
  int i = blockIdx.x * blockDim.x + threadIdx.x;
  int lane = threadIdx.x & 63;
  int v = (i < N_NODES) ? deg[i] : 0;
  int sum = v;
#pragma unroll
  for (int off = 1; off < 64; off <<= 1) {
    int t = __shfl_up(sum, off);
    if (lane >= off) sum += t;
  }
  int excl = sum - v;
  int waveTot = __shfl(sum, 63);
  int base = 0;
  if (lane == 63) base = atomicAdd(counter, waveTot);
  base = __shfl(base, 63);
  if (i < N_NODES) {
    start[i] = base + excl;
    cursor[i] = base + excl;
  }
}

__global__ void scatter_kernel(const int* __restrict__ src, const int* __restrict__ dst,
                               int* __restrict__ cursor, int* __restrict__ csr) {
  int e = blockIdx.x * blockDim.x + threadIdx.x;
  if (e < EDGES) {
    int pos = atomicAdd(&cursor[dst[e]], 1);
    csr[pos] = src[e];
  }
}

// ---------------------------------------------------------------------------
// Attention. No-max softmax (round-10 verified: alpha bounded, shift-invariant)
// + __expf. K/V are fp8 (half bytes, 4-inst decode); Q/skip bf16.
// attn1: one wave per (node, head); attn2: one wave per node, dual-head.
// 4 x 16-lane groups process 4 edges in parallel; group merge = pure adds.
// ---------------------------------------------------------------------------
#define INV_SQRT_CH 0.08838834764831845f

// layer 1 (pair p, hh = blockIdx.y): row 1536 B; head base hh*768:
// q bf16 @0, s bf16 @256, k fp8 @512, v fp8 @640.
__global__ __launch_bounds__(256) void attn1_kernel(
    const char* __restrict__ BIG, const int* __restrict__ start,
    const int* __restrict__ deg, const int* __restrict__ csr,
    ushort_t* __restrict__ H1b, int p) {
  int wave = threadIdx.x >> 6, lane = threadIdx.x & 63;
  int li = lane & 15, g = lane >> 4;
  int i = blockIdx.x * 4 + wave;
  if (i >= N_NODES) return;
  int hh = blockIdx.y;
  int beg = start[i], end = beg + deg[i];
  const char* hb = BIG + hh * 768;
  float q[8];
  unpack8(*(const uint4*)(hb + (size_t)i * 1536 + li * 16), q);
  float s = 0.f, a[8] = {};
  for (int e0 = beg; e0 < end; e0 += 4) {
    int eg = e0 + g;
    bool valid = eg < end;
    int j = csr[valid ? eg : beg];
    const char* jp = hb + (size_t)j * 1536;
    uint2 kw = *(const uint2*)(jp + 512 + li * 8);
    uint2 vw = *(const uint2*)(jp + 640 + li * 8);
    float kf[8]; unpack8_fp8(kw, kf);
    float pd = q[0]*kf[0]+q[1]*kf[1]+q[2]*kf[2]+q[3]*kf[3]+
               q[4]*kf[4]+q[5]*kf[5]+q[6]*kf[6]+q[7]*kf[7];
    pd += __shfl_xor(pd, 1);
    pd += __shfl_xor(pd, 2);
    pd += __shfl_xor(pd, 4);
    pd += __shfl_xor(pd, 8);
    float w = valid ? __expf(pd * INV_SQRT_CH) : 0.f;
    float vf[8]; unpack8_fp8(vw, vf);
    s += w;
#pragma unroll
    for (int c = 0; c < 8; ++c) a[c] = fmaf(w, vf[c], a[c]);
  }
#pragma unroll
  for (int ox = 16; ox <= 32; ox <<= 1) {
    s += __shfl_xor(s, ox);
#pragma unroll
    for (int c = 0; c < 8; ++c) a[c] += __shfl_xor(a[c], ox);
  }
  if (g != 0) return;
  float inv = 1.f / (s + 1e-16f);
  float sk[8];
  unpack8(*(const uint4*)(hb + (size_t)i * 1536 + 256 + li * 16), sk);
  uint4 ow;
  uint_t* op = (uint_t*)&ow;
#pragma unroll
  for (int c = 0; c < 4; ++c) {
    float o0 = a[2 * c] * inv + sk[2 * c];
    float o1 = a[2 * c + 1] * inv + sk[2 * c + 1];
    o0 = o0 > 0.f ? o0 : expm1f(o0);
    o1 = o1 > 0.f ? o1 : expm1f(o1);
    op[c] = (uint_t)f2bf(o0) | ((uint_t)f2bf(o1) << 16);
  }
  *(uint4*)(H1b + (size_t)i * HID + (2 * p + hh) * CH + li * 8) = ow;
}

// layer 2: row 1280 B; head base hh*512: q bf16 @0, k fp8 @256, v fp8 @384;
// skip bf16 @1024 (valid only on first pass). Dual-head per edge-iter.
__global__ __launch_bounds__(256) void attn2_kernel(
    const char* __restrict__ BIG, const int* __restrict__ start,
    const int* __restrict__ deg, const int* __restrict__ csr,
    float* __restrict__ S2, int first) {
  int wave = threadIdx.x >> 6, lane = threadIdx.x & 63;
  int li = lane & 15, g = lane >> 4;
  int i = blockIdx.x * 4 + wave;
  if (i >= N_NODES) return;
  int beg = start[i], end = beg + deg[i];
  const char* ip = BIG + (size_t)i * 1280;
  float q0[8], q1[8];
  unpack8(*(const uint4*)(ip + li * 16), q0);
  unpack8(*(const uint4*)(ip + 512 + li * 16), q1);
  float s0 = 0.f, s1 = 0.f, a0[8] = {}, a1[8] = {};
  for (int e0 = beg; e0 < end; e0 += 4) {
    int eg = e0 + g;
    bool valid = eg < end;
    int j = csr[valid ? eg : beg];
    const char* jp = BIG + (size_t)j * 1280;
    uint2 kw0 = *(const uint2*)(jp + 256 + li * 8);
    uint2 vw0 = *(const uint2*)(jp + 384 + li * 8);
    uint2 kw1 = *(const uint2*)(jp + 768 + li * 8);
    uint2 vw1 = *(const uint2*)(jp + 896 + li * 8);
    float kf[8];
    unpack8_fp8(kw0, kf);
    float p0 = q0[0]*kf[0]+q0[1]*kf[1]+q0[2]*kf[2]+q0[3]*kf[3]+
               q0[4]*kf[4]+q0[5]*kf[5]+q0[6]*kf[6]+q0[7]*kf[7];
    unpack8_fp8(kw1, kf);
    float p1 = q1[0]*kf[0]+q1[1]*kf[1]+q1[2]*kf[2]+q1[3]*kf[3]+
               q1[4]*kf[4]+q1[5]*kf[5]+q1[6]*kf[6]+q1[7]*kf[7];
#pragma unroll
    for (int ox = 1; ox <= 8; ox <<= 1) {
      p0 += __shfl_xor(p0, ox);
      p1 += __shfl_xor(p1, ox);
    }
    float w0 = valid ? __expf(p0 * INV_SQRT_CH) : 0.f;
    float w1 = valid ? __expf(p1 * INV_SQRT_CH) : 0.f;
    float vf[8];
    unpack8_fp8(vw0, vf);
    s0 += w0;
#pragma unroll
    for (int c = 0; c < 8; ++c) a0[c] = fmaf(w0, vf[c], a0[c]);
    unpack8_fp8(vw1, vf);
    s1 += w1;
#pragma unroll
    for (int c = 0; c < 8; ++c) a1[c] = fmaf(w1, vf[c], a1[c]);
  }
#pragma unroll
  for (int ox = 16; ox <= 32; ox <<= 1) {
    s0 += __shfl_xor(s0, ox);
    s1 += __shfl_xor(s1, ox);
#pragma unroll
    for (int c = 0; c < 8; ++c) {
      a0[c] += __shfl_xor(a0[c], ox);
      a1[c] += __shfl_xor(a1[c], ox);
    }
  }
  if (g != 0) return;
  float inv0 = 0.25f / (s0 + 1e-16f), inv1 = 0.25f / (s1 + 1e-16f);
  float* sp = S2 + (size_t)i * CH + li * 8;
  if (first) {
    float sk[8];
    unpack8(*(const uint4*)(ip + 1024 + li * 16), sk);
#pragma unroll
    for (int c = 0; c < 8; ++c) sp[c] = sk[c] + a0[c] * inv0 + a1[c] * inv1;
  } else {
#pragma unroll
    for (int c = 0; c < 8; ++c) sp[c] += a0[c] * inv0 + a1[c] * inv1;
  }
}

// ---------------------------------------------------------------------------
// Fused pool (segment loop, no atomics — batch is sorted) + ELU + classifier
// + log_softmax. One block of 256 per graph: 2 rows x 128 ch.
// ---------------------------------------------------------------------------
__global__ __launch_bounds__(256) void pool_cls(
    const float* __restrict__ S2, const int* __restrict__ gstart,
    const int* __restrict__ gend, const float* __restrict__ Wfc,
    const float* __restrict__ bfc, float* __restrict__ out) {
  int g = blockIdx.x;
  int t = threadIdx.x;
  int c = t & (CH - 1), rr = t >> 7;
  int s0 = gstart[g], e0 = gend[g];
  float sum = 0.f;
  for (int i = s0 + rr; i < e0; i += 2) {
    float v = S2[(size_t)i * CH + c];
    v = v > 0.f ? v : expm1f(v);
    sum += v;
  }
  __shared__ float sh[256];
  __shared__ float p[CH];
  __shared__ float red[CH];
  __shared__ float logits[NCLS];
  sh[t] = sum;
  __syncthreads();
  if (t < CH) {
    float cnt = fmaxf((float)(e0 - s0), 1.f);
    p[t] = (sh[t] + sh[t + CH]) / cnt;
  }
  for (int cc = 0; cc < NCLS; ++cc) {
    __syncthreads();
    if (t < CH) red[t] = p[t] * Wfc[t * NCLS + cc];
    __syncthreads();
    for (int off = 64; off > 0; off >>= 1) {
      if (t < off) red[t] += red[t + off];
      __syncthreads();
    }
    if (t == 0) logits[cc] = red[0] + bfc[cc];
  }
  __syncthreads();
  if (t == 0) {
    float mx = -INFINITY;
    for (int cc = 0; cc < NCLS; ++cc) mx = fmaxf(mx, logits[cc]);
    float se = 0.f;
    for (int cc = 0; cc < NCLS; ++cc) se += expf(logits[cc] - mx);
    float ls = mx + logf(se);
    for (int cc = 0; cc < NCLS; ++cc) out[g * NCLS + cc] = logits[cc] - ls;
  }
}

// ---------------------------------------------------------------------------
extern "C" void kernel_launch(void* const* d_in, const int* in_sizes, int n_in,
                              void* d_out, int out_size, void* d_ws, size_t ws_size,
                              hipStream_t stream) {
  const float* x    = (const float*)d_in[0];
  const int*   ei   = (const int*)d_in[1];
  const int*   batch= (const int*)d_in[2];
  const float* Wq1 = (const float*)d_in[3];  const float* bq1 = (const float*)d_in[4];
  const float* Wk1 = (const float*)d_in[5];  const float* bk1 = (const float*)d_in[6];
  const float* Wv1 = (const float*)d_in[7];  const float* bv1 = (const float*)d_in[8];
  const float* Ws1 = (const float*)d_in[9];  const float* bs1 = (const float*)d_in[10];
  const float* Wq2 = (const float*)d_in[11]; const float* bq2 = (const float*)d_in[12];
  const float* Wk2 = (const float*)d_in[13]; const float* bk2 = (const float*)d_in[14];
  const float* Wv2 = (const float*)d_in[15]; const float* bv2 = (const float*)d_in[16];
  const float* Ws2 = (const float*)d_in[17]; const float* bs2 = (const float*)d_in[18];
  const float* Wfc = (const float*)d_in[19]; const float* bfc = (const float*)d_in[20];
  float* out = (float*)d_out;

  // Workspace (~157 MB). S2 (fp32 N*128 = 25.6MB) aliases xb (dead after L1 GEMMs).
  ushort_t* xb   = (ushort_t*)d_ws;                    // N x 256 bf16 (25.6 MB)
  float*    S2   = (float*)d_ws;                       // N x 128 fp32 (aliases xb)
  char*     BIG  = (char*)(xb + (size_t)N_NODES * FEAT);  // N x 1536 B (76.8 MB)
  ushort_t* H1b  = (ushort_t*)(BIG + (size_t)N_NODES * 1536); // N x 512 bf16
  ushort_t* W1t  = H1b + (size_t)N_NODES * HID;        // 2048*256
  float*    Bh1  = (float*)(W1t + L1_W);               // 2048
  ushort_t* W2t  = (ushort_t*)(Bh1 + 2048);            // 1664*512
  float*    Bh2  = (float*)(W2t + L2_W);               // 1664
  int* deg    = (int*)(Bh2 + 1664);
  int* start  = deg + N_NODES;
  int* cursor = start + N_NODES;
  int* csr    = cursor + N_NODES;
  int* gstart = csr + EDGES;
  int* gend   = gstart + NGRAPH;
  int* counter= gend + NGRAPH;

  const int* srcp = ei;
  const int* dstp = ei + EDGES;

  // ---- prep ----
  cvt_bf16_kernel<<<(N_NODES * FEAT / 4 + 255) / 256, 256, 0, stream>>>(x, xb, N_NODES * FEAT / 4);
  prep_tp<<<T1 + T2, 256, 0, stream>>>(Wq1, Wk1, Wv1, Ws1, Wq2, Wk2, Wv2, Ws2, W1t, W2t);
  bias_kernel<<<(2048 + 1664 + 255) / 256, 256, 0, stream>>>(
      bq1, bk1, bv1, bs1, bq2, bk2, bv2, bs2, Bh1, Bh2);

  // ---- CSR build ----
  zero_kernel<<<(N_NODES + 255) / 256, 256, 0, stream>>>(deg, counter, gstart, gend);
  hist_bounds_kernel<<<(EDGES + 255) / 256, 256, 0, stream>>>(dstp, deg, batch, gstart, gend);
  alloc_kernel<<<(N_NODES + 255) / 256, 256, 0, stream>>>(deg, counter, start, cursor);
  scatter_kernel<<<(EDGES + 255) / 256, 256, 0, stream>>>(srcp, dstp, cursor, csr);

  const int gx8 = 49 * 8;               // 392 row tiles (padded; kernel guards)
  const int ga = (N_NODES + 3) / 4;     // 12500

  // ---- layer 1: per head-pair, GEMM (1024 cols, mixed out) + attention ----
  for (int p = 0; p < 2; ++p) {
    gemm_bt<<<gx8 * 8, 256, 0, stream>>>(
        xb, W1t + (size_t)p * 1024 * FEAT, Bh1 + p * 1024, BIG, N_NODES, FEAT, 8, 1);
    attn1_kernel<<<dim3(ga, 2), 256, 0, stream>>>(BIG, start, deg, csr, H1b, p);
  }

  // ---- layer 2: pair0 GEMM includes skip block (896 cols); attn2 -> S2 ----
  gemm_bt<<<gx8 * 7, 256, 0, stream>>>(
      H1b, W2t, Bh2, BIG, N_NODES, HID, 7, 2);
  attn2_kernel<<<ga, 256, 0, stream>>>(BIG, start, deg, csr, S2, 1);
  gemm_bt<<<gx8 * 6, 256, 0, stream>>>(
      H1b, W2t + (size_t)896 * HID, Bh2 + 896, BIG, N_NODES, HID, 6, 2);
  attn2_kernel<<<ga, 256, 0, stream>>>(BIG, start, deg, csr, S2, 0);

  // ---- fused pool + classify ----
  pool_cls<<<NGRAPH, 256, 0, stream>>>(S2, gstart, gend, Wfc, bfc, out);
}

// Round 12
// 588.807 us; speedup vs baseline: 1.1703x; 1.0594x over previous
//
#include <hip/hip_runtime.h>
#include <math.h>
#include <stdint.h>

#define N_NODES 50000
#define FEAT    256
#define EDGES   200000
#define HEADS   4
#define CH      128
#define HID     512   // HEADS*CH
#define NGRAPH  256
#define NCLS    10

typedef unsigned short ushort_t;
typedef unsigned int uint_t;
typedef __attribute__((ext_vector_type(8))) short bf16x8;
typedef __attribute__((ext_vector_type(4))) float f32x4;
typedef __attribute__((ext_vector_type(2))) float f32x2;

__device__ __forceinline__ ushort_t f2bf(float f) {  // round-to-nearest-even
  uint_t u = __float_as_uint(f);
  u += 0x7FFF + ((u >> 16) & 1);
  return (ushort_t)(u >> 16);
}
__device__ __forceinline__ float bf2f(ushort_t h) {
  return __uint_as_float(((uint_t)h) << 16);
}
__device__ __forceinline__ void unpack8(uint4 w, float* f) {
  f[0] = bf2f((ushort_t)w.x); f[1] = bf2f((ushort_t)(w.x >> 16));
  f[2] = bf2f((ushort_t)w.y); f[3] = bf2f((ushort_t)(w.y >> 16));
  f[4] = bf2f((ushort_t)w.z); f[5] = bf2f((ushort_t)(w.z >> 16));
  f[6] = bf2f((ushort_t)w.w); f[7] = bf2f((ushort_t)(w.w >> 16));
}
// 8 x fp8(e4m3) -> 8 x f32 via v_cvt_pk_f32_fp8 (4 insts)
__device__ __forceinline__ void unpack8_fp8(uint2 w, float* f) {
  f32x2 a = __builtin_amdgcn_cvt_pk_f32_fp8((int)w.x, false);
  f32x2 b = __builtin_amdgcn_cvt_pk_f32_fp8((int)w.x, true);
  f32x2 c = __builtin_amdgcn_cvt_pk_f32_fp8((int)w.y, false);
  f32x2 d = __builtin_amdgcn_cvt_pk_f32_fp8((int)w.y, true);
  f[0] = a[0]; f[1] = a[1]; f[2] = b[0]; f[3] = b[1];
  f[4] = c[0]; f[5] = c[1]; f[6] = d[0]; f[7] = d[1];
}
__device__ __forceinline__ uint_t pack4_fp8(float f0, float f1, float f2, float f3) {
  int v = __builtin_amdgcn_cvt_pk_fp8_f32(f0, f1, 0, false);
  v = __builtin_amdgcn_cvt_pk_fp8_f32(f2, f3, v, true);
  return (uint_t)v;
}

// ---------------------------------------------------------------------------
// bf16 MFMA GEMM with mixed-precision blocked output.
// 128x128 tile, BK=32, 16 KB LDS. XCD-swizzled 1-D grid (round-7: FETCH
// 180->34 MB). Fragment swizzle (r>>1)&3 and epilogue swizzle rq<<4 are
// 2-way max (round-8: SQ_LDS_BANK_CONFLICT == 0). Do not touch those.
// Output rows, byte-addressed, per-128-col-block mapping:
//  mode 1 (L1 pair): row 1536 B, per head (768 B): q bf16 @0, s bf16 @256,
//                    k fp8 @512, v fp8 @640.  Weight col order q,k,v,s.
//  mode 2 (L2 all):  row 2304 B, per head (512 B, hh=0..3): q bf16 @hh*512,
//                    k fp8 @+256, v fp8 @+384; skip bf16 @2048
//                    (cols [768,896) in W2t order h0 h1 | skip | h2 h3).
// ---------------------------------------------------------------------------
__global__ __launch_bounds__(256) void gemm_bt(
    const ushort_t* __restrict__ A, const ushort_t* __restrict__ Bt,
    const float* __restrict__ bias, char* __restrict__ Cb,
    int M, int K, int ncol, int mode) {
  __shared__ __align__(16) ushort_t smem[8192];   // 16 KB total
  ushort_t* sA = smem;                            // 128 x 32
  ushort_t* sB = smem + 4096;                     // 128 x 32
  const int tid = threadIdx.x;
  const int lane = tid & 63, wave = tid >> 6;
  const int wr = wave >> 1, wc = wave & 1;

  // XCD-aware decode: rt = grp*8 + (b%8), c = (b/8)%ncol
  int b = blockIdx.x;
  int per = ncol << 3;
  int grp = b / per;
  int rem = b - grp * per;
  int rloc = rem & 7;
  int c = rem >> 3;
  const int rowBase = (grp * 8 + rloc) * 128;
  const int colBase = c * 128;
  if (rowBase >= M) return;

  f32x4 acc[4][4] = {};

  for (int k0 = 0; k0 < K; k0 += 32) {
#pragma unroll
    for (int l = 0; l < 2; ++l) {
      int slot = l * 256 + tid;           // 0..511
      int rl = slot >> 2;                 // row/col 0..127
      int pos = slot & 3;                 // stored chunk slot
      int cg = pos ^ ((rl >> 1) & 3);     // swizzled global chunk
      {
        int row = rowBase + rl;
        row = row < M ? row : M - 1;      // clamp tail (epilogue guards)
        const ushort_t* gp = A + (size_t)row * K + k0 + cg * 8;
        __builtin_amdgcn_global_load_lds(
            (const __attribute__((address_space(1))) uint_t*)gp,
            (__attribute__((address_space(3))) uint_t*)(sA + slot * 8),
            16, 0, 0);
      }
      {
        int n = colBase + rl;
        const ushort_t* gp = Bt + (size_t)n * K + k0 + cg * 8;
        __builtin_amdgcn_global_load_lds(
            (const __attribute__((address_space(1))) uint_t*)gp,
            (__attribute__((address_space(3))) uint_t*)(sB + slot * 8),
            16, 0, 0);
      }
    }
    __syncthreads();
    const int fr = lane & 15, c0 = lane >> 4;
    bf16x8 af[4], bfr[4];
#pragma unroll
    for (int i = 0; i < 4; ++i) {
      int r = wr * 64 + i * 16 + fr;
      af[i] = *(const bf16x8*)(sA + r * 32 + ((c0 ^ ((r >> 1) & 3)) * 8));
      int n = wc * 64 + i * 16 + fr;
      bfr[i] = *(const bf16x8*)(sB + n * 32 + ((c0 ^ ((n >> 1) & 3)) * 8));
    }
#pragma unroll
    for (int i = 0; i < 4; ++i)
#pragma unroll
      for (int j = 0; j < 4; ++j)
        acc[i][j] = __builtin_amdgcn_mfma_f32_16x16x32_bf16(af[i], bfr[j], acc[i][j], 0, 0, 0);
    __syncthreads();
  }

  // ---- output block -> (byte offset, dtype), wave-uniform ----
  int koff, rowStride, isfp8;
  if (mode == 1) {
    rowStride = 1536;
    int hh = colBase >> 9, sel = (colBase >> 7) & 3;      // q,k,v,s
    koff = hh * 768 + (sel == 0 ? 0 : sel == 3 ? 256 : sel == 1 ? 512 : 640);
    isfp8 = (sel == 1 || sel == 2);
  } else {
    rowStride = 2304;
    if (colBase >= 768 && colBase < 896) { koff = 2048; isfp8 = 0; }
    else {
      int n2 = (colBase < 768) ? colBase : colBase - 896;
      int hb = (colBase < 768) ? 0 : 2;
      int hh = hb + n2 / 384, r = n2 % 384, sel = r >> 7;  // q,k,v
      koff = hh * 512 + (sel == 0 ? 0 : sel == 1 ? 256 : 384);
      isfp8 = (sel >= 1);
    }
  }

  // Epilogue: per-wave LDS repack in two 32-row halves (4 KB/wave region).
  // C/D layout col=lane&15, row=(lane>>4)*4+reg (m89-verified).
  ushort_t* wbuf = smem + wave * 2048;    // 32 x 64 bf16
  const int rq = lane >> 4, fc = lane & 15;
  float bv[4];
#pragma unroll
  for (int j = 0; j < 4; ++j) bv[j] = bias[colBase + wc * 64 + j * 16 + fc];
#pragma unroll
  for (int h = 0; h < 2; ++h) {
#pragma unroll
    for (int ii = 0; ii < 2; ++ii) {
      int i = h * 2 + ii;
#pragma unroll
      for (int j = 0; j < 4; ++j)
#pragma unroll
        for (int r = 0; r < 4; ++r) {
          int rl = ii * 16 + rq * 4 + r;          // 0..31 ; (rl>>2)&3 == rq
          int cl = j * 16 + fc;                   // 0..63
          int cs = cl ^ (rq << 4);                // rq -> bank octet
          wbuf[rl * 64 + cs] = f2bf(acc[i][j][r] + bv[j]);
        }
    }
    // read back: lanes 0..7 cover all 32 banks (ci*4); remap chunk by rq
    int ci = lane & 7;
    int rbase = lane >> 3;                         // 0..7
#pragma unroll
    for (int rg = 0; rg < 4; ++rg) {
      int rr = rg * 8 + rbase;                     // 0..31
      int rowg = rowBase + wr * 64 + h * 32 + rr;
      int cg = ci ^ (((rr >> 2) & 3) << 1);
      uint4 val = *(const uint4*)(wbuf + rr * 64 + (ci << 3));
      if (rowg < M) {
        char* dstRow = Cb + (size_t)rowg * rowStride + koff;
        if (!isfp8) {
          *(uint4*)(dstRow + (wc * 64 + cg * 8) * 2) = val;
        } else {
          float f[8];
          f[0] = bf2f((ushort_t)val.x); f[1] = bf2f((ushort_t)(val.x >> 16));
          f[2] = bf2f((ushort_t)val.y); f[3] = bf2f((ushort_t)(val.y >> 16));
          f[4] = bf2f((ushort_t)val.z); f[5] = bf2f((ushort_t)(val.z >> 16));
          f[6] = bf2f((ushort_t)val.w); f[7] = bf2f((ushort_t)(val.w >> 16));
          uint2 o;
          o.x = pack4_fp8(f[0], f[1], f[2], f[3]);
          o.y = pack4_fp8(f[4], f[5], f[6], f[7]);
          *(uint2*)(dstRow + wc * 64 + cg * 8) = o;
        }
      }
    }
  }
}

// ---------------------------------------------------------------------------
// prep_all: one launch, four independent regions branch on blockIdx.x:
//  [0, NB_CVT)           : x fp32 -> bf16 (vectorized)
//  [NB_CVT, +NB_TP)      : weight 32x32 tile transposes -> W1t / W2t
//  [.., +NB_BIAS)        : bias permute -> Bh1 / Bh2
//  [.., +NB_ZERO)        : zero deg/counter/gstart/gend
// ---------------------------------------------------------------------------
#define L1_W   (2048 * FEAT)
#define L2_W   (1664 * HID)
#define T1     512   // (2048/32)*(256/32)
#define T2     832   // (1664/32)*(512/32)
#define NB_CVT  12500
#define NB_TP   (T1 + T2)
#define NB_BIAS 15
#define NB_ZERO 196

__global__ __launch_bounds__(256) void prep_all(
    const float* __restrict__ x, ushort_t* __restrict__ xb,
    const float* __restrict__ Wq1, const float* __restrict__ Wk1,
    const float* __restrict__ Wv1, const float* __restrict__ Ws1,
    const float* __restrict__ Wq2, const float* __restrict__ Wk2,
    const float* __restrict__ Wv2, const float* __restrict__ Ws2,
    const float* __restrict__ bq1, const float* __restrict__ bk1,
    const float* __restrict__ bv1, const float* __restrict__ bs1,
    const float* __restrict__ bq2, const float* __restrict__ bk2,
    const float* __restrict__ bv2, const float* __restrict__ bs2,
    ushort_t* __restrict__ W1t, ushort_t* __restrict__ W2t,
    float* __restrict__ Bh1, float* __restrict__ Bh2,
    int* __restrict__ deg, int* __restrict__ counter,
    int* __restrict__ gstart, int* __restrict__ gend) {
  __shared__ float tile[32][33];
  int blk = blockIdx.x;
  if (blk < NB_CVT) {
    int i = blk * 256 + threadIdx.x;            // n4 = 3.2M exactly
    float4 f = *(const float4*)(x + (size_t)i * 4);
    uint_t lo = (uint_t)f2bf(f.x) | ((uint_t)f2bf(f.y) << 16);
    uint_t hi = (uint_t)f2bf(f.z) | ((uint_t)f2bf(f.w) << 16);
    ((uint2*)xb)[i] = make_uint2(lo, hi);
    return;
  }
  blk -= NB_CVT;
  if (blk < NB_TP) {
    int t = blk;
    const float* W; int ldw, c0, n0, k0, ldk; ushort_t* dst;
    if (t < T1) {
      int nb = t >> 3, kb = t & 7;
      n0 = nb * 32; k0 = kb * 32; ldk = FEAT; dst = W1t;
      int p = n0 >> 10, n1 = n0 & 1023, hh = n1 >> 9, sel = (n1 >> 7) & 3;
      c0 = (2 * p + hh) * CH + (n1 & (CH - 1));
      W = sel == 0 ? Wq1 : sel == 1 ? Wk1 : sel == 2 ? Wv1 : Ws1;
      ldw = HID;
    } else {
      t -= T1;
      int nb = t >> 4, kb = t & 15;
      n0 = nb * 32; k0 = kb * 32; ldk = HID; dst = W2t;
      if (n0 < 768 || n0 >= 896) {
        int n2 = (n0 < 768) ? n0 : n0 - 896;
        int hb = (n0 < 768) ? 0 : 2;
        int hh = hb + n2 / 384, r = n2 % 384, sel = r >> 7;
        c0 = hh * CH + (r & (CH - 1));
        W = sel == 0 ? Wq2 : sel == 1 ? Wk2 : Wv2;
        ldw = HID;
      } else {
        c0 = n0 - 768; W = Ws2; ldw = CH;
      }
    }
    int col = threadIdx.x & 31, rw = threadIdx.x >> 5;
#pragma unroll
    for (int ph = 0; ph < 4; ++ph) {
      int kk = rw + ph * 8;
      tile[kk][col] = W[(size_t)(k0 + kk) * ldw + c0 + col];
    }
    __syncthreads();
#pragma unroll
    for (int ph = 0; ph < 4; ++ph) {
      int dn = rw + ph * 8;
      dst[(size_t)(n0 + dn) * ldk + k0 + col] = f2bf(tile[col][dn]);
    }
    return;
  }
  blk -= NB_TP;
  if (blk < NB_BIAS) {
    int n = blk * 256 + threadIdx.x;
    if (n < 2048) {
      int p = n >> 10, n1 = n & 1023, hh = n1 >> 9, sel = (n1 >> 7) & 3;
      int c = (2 * p + hh) * CH + (n1 & (CH - 1));
      const float* bb = sel == 0 ? bq1 : sel == 1 ? bk1 : sel == 2 ? bv1 : bs1;
      Bh1[n] = bb[c];
    } else if (n < 2048 + 1664) {
      int n2 = n - 2048;
      if (n2 < 768 || n2 >= 896) {
        int nn = (n2 < 768) ? n2 : n2 - 896;
        int hb = (n2 < 768) ? 0 : 2;
        int hh = hb + nn / 384, r = nn % 384, sel = r >> 7;
        int c = hh * CH + (r & (CH - 1));
        const float* bb = sel == 0 ? bq2 : sel == 1 ? bk2 : bv2;
        Bh2[n2] = bb[c];
      } else {
        Bh2[n2] = bs2[n2 - 768];
      }
    }
    return;
  }
  blk -= NB_BIAS;
  {
    int i = blk * 256 + threadIdx.x;
    if (i < N_NODES) deg[i] = 0;
    if (i < NGRAPH) { gstart[i] = 0; gend[i] = 0; }
    if (i == 0) counter[0] = 0;
  }
}

// ---------------------------------------------------------------------------
// CSR build: hist+bounds -> alloc (wave atomic) -> scatter
// ---------------------------------------------------------------------------
__global__ void hist_bounds_kernel(const int* __restrict__ dst, int* __restrict__ deg,
                                   const int* __restrict__ batch,
                                   int* __restrict__ gstart, int* __restrict__ gend) {
  int t = blockIdx.x * blockDim.x + threadIdx.x;
  if (t < EDGES) atomicAdd(&deg[dst[t]], 1);
  if (t < N_NODES) {
    int b = batch[t];
    if (t == 0 || batch[t - 1] != b) gstart[b] = t;
    if (t == N_NODES - 1 || batch[t + 1] != b) gend[b] = t + 1;
  }
}

__global__ void alloc_kernel(const int* __restrict__ deg, int* __restrict__ counter,
                             int* __restrict__ start, int* __restrict__ cursor) {
  int i = blockIdx.x * blockDim.x + threadIdx.x;
  int lane = threadIdx.x & 63;
  int v = (i < N_NODES) ? deg[i] : 0;
  int sum = v;
#pragma unroll
  for (int off = 1; off < 64; off <<= 1) {
    int t = __shfl_up(sum, off);
    if (lane >= off) sum += t;
  }
  int excl = sum - v;
  int waveTot = __shfl(sum, 63);
  int base = 0;
  if (lane == 63) base = atomicAdd(counter, waveTot);
  base = __shfl(base, 63);
  if (i < N_NODES) {
    start[i] = base + excl;
    cursor[i] = base + excl;
  }
}

__global__ void scatter_kernel(const int* __restrict__ src, const int* __restrict__ dst,
                               int* __restrict__ cursor, int* __restrict__ csr) {
  int e = blockIdx.x * blockDim.x + threadIdx.x;
  if (e < EDGES) {
    int pos = atomicAdd(&cursor[dst[e]], 1);
    csr[pos] = src[e];
  }
}

// ---------------------------------------------------------------------------
// Attention. No-max softmax (round-10 verified: alpha bounded, shift-invariant)
// + __expf. K/V fp8 (4-inst decode); Q/skip bf16.
// attn1: one wave per (node, head); attn2: one wave per (node, head-pair),
// dual-head. 4 x 16-lane groups process 4 edges in parallel; merges = adds.
// ---------------------------------------------------------------------------
#define INV_SQRT_CH 0.08838834764831845f

// layer 1 (pair p, hh = blockIdx.y): row 1536 B; head base hh*768:
// q bf16 @0, s bf16 @256, k fp8 @512, v fp8 @640.
__global__ __launch_bounds__(256) void attn1_kernel(
    const char* __restrict__ BIG, const int* __restrict__ start,
    const int* __restrict__ deg, const int* __restrict__ csr,
    ushort_t* __restrict__ H1b, int p) {
  int wave = threadIdx.x >> 6, lane = threadIdx.x & 63;
  int li = lane & 15, g = lane >> 4;
  int i = blockIdx.x * 4 + wave;
  if (i >= N_NODES) return;
  int hh = blockIdx.y;
  int beg = start[i], end = beg + deg[i];
  const char* hb = BIG + hh * 768;
  float q[8];
  unpack8(*(const uint4*)(hb + (size_t)i * 1536 + li * 16), q);
  float s = 0.f, a[8] = {};
  for (int e0 = beg; e0 < end; e0 += 4) {
    int eg = e0 + g;
    bool valid = eg < end;
    int j = csr[valid ? eg : beg];
    const char* jp = hb + (size_t)j * 1536;
    uint2 kw = *(const uint2*)(jp + 512 + li * 8);
    uint2 vw = *(const uint2*)(jp + 640 + li * 8);
    float kf[8]; unpack8_fp8(kw, kf);
    float pd = q[0]*kf[0]+q[1]*kf[1]+q[2]*kf[2]+q[3]*kf[3]+
               q[4]*kf[4]+q[5]*kf[5]+q[6]*kf[6]+q[7]*kf[7];
    pd += __shfl_xor(pd, 1);
    pd += __shfl_xor(pd, 2);
    pd += __shfl_xor(pd, 4);
    pd += __shfl_xor(pd, 8);
    float w = valid ? __expf(pd * INV_SQRT_CH) : 0.f;
    float vf[8]; unpack8_fp8(vw, vf);
    s += w;
#pragma unroll
    for (int c = 0; c < 8; ++c) a[c] = fmaf(w, vf[c], a[c]);
  }
#pragma unroll
  for (int ox = 16; ox <= 32; ox <<= 1) {
    s += __shfl_xor(s, ox);
#pragma unroll
    for (int c = 0; c < 8; ++c) a[c] += __shfl_xor(a[c], ox);
  }
  if (g != 0) return;
  float inv = 1.f / (s + 1e-16f);
  float sk[8];
  unpack8(*(const uint4*)(hb + (size_t)i * 1536 + 256 + li * 16), sk);
  uint4 ow;
  uint_t* op = (uint_t*)&ow;
#pragma unroll
  for (int c = 0; c < 4; ++c) {
    float o0 = a[2 * c] * inv + sk[2 * c];
    float o1 = a[2 * c + 1] * inv + sk[2 * c + 1];
    o0 = o0 > 0.f ? o0 : expm1f(o0);
    o1 = o1 > 0.f ? o1 : expm1f(o1);
    op[c] = (uint_t)f2bf(o0) | ((uint_t)f2bf(o1) << 16);
  }
  *(uint4*)(H1b + (size_t)i * HID + (2 * p + hh) * CH + li * 8) = ow;
}

// layer 2: row 2304 B; head hh base hh*512: q bf16 @0, k fp8 @256, v fp8 @384;
// pair p = blockIdx.y handles hh = 2p, 2p+1. Writes 0.25*(m0+m1) as bf16 to
// PairOut[p][i][c]; pool adds skip (BIG @2048) + both pairs.
__global__ __launch_bounds__(256) void attn2_kernel(
    const char* __restrict__ BIG, const int* __restrict__ start,
    const int* __restrict__ deg, const int* __restrict__ csr,
    ushort_t* __restrict__ PairOut) {
  int wave = threadIdx.x >> 6, lane = threadIdx.x & 63;
  int li = lane & 15, g = lane >> 4;
  int i = blockIdx.x * 4 + wave;
  if (i >= N_NODES) return;
  int p = blockIdx.y;
  int qo0 = p * 1024, qo1 = p * 1024 + 512;
  int beg = start[i], end = beg + deg[i];
  const char* ip = BIG + (size_t)i * 2304;
  float q0[8], q1[8];
  unpack8(*(const uint4*)(ip + qo0 + li * 16), q0);
  unpack8(*(const uint4*)(ip + qo1 + li * 16), q1);
  float s0 = 0.f, s1 = 0.f, a0[8] = {}, a1[8] = {};
  for (int e0 = beg; e0 < end; e0 += 4) {
    int eg = e0 + g;
    bool valid = eg < end;
    int j = csr[valid ? eg : beg];
    const char* jp = BIG + (size_t)j * 2304;
    uint2 kw0 = *(const uint2*)(jp + qo0 + 256 + li * 8);
    uint2 vw0 = *(const uint2*)(jp + qo0 + 384 + li * 8);
    uint2 kw1 = *(const uint2*)(jp + qo1 + 256 + li * 8);
    uint2 vw1 = *(const uint2*)(jp + qo1 + 384 + li * 8);
    float kf[8];
    unpack8_fp8(kw0, kf);
    float p0 = q0[0]*kf[0]+q0[1]*kf[1]+q0[2]*kf[2]+q0[3]*kf[3]+
               q0[4]*kf[4]+q0[5]*kf[5]+q0[6]*kf[6]+q0[7]*kf[7];
    unpack8_fp8(kw1, kf);
    float p1 = q1[0]*kf[0]+q1[1]*kf[1]+q1[2]*kf[2]+q1[3]*kf[3]+
               q1[4]*kf[4]+q1[5]*kf[5]+q1[6]*kf[6]+q1[7]*kf[7];
#pragma unroll
    for (int ox = 1; ox <= 8; ox <<= 1) {
      p0 += __shfl_xor(p0, ox);
      p1 += __shfl_xor(p1, ox);
    }
    float w0 = valid ? __expf(p0 * INV_SQRT_CH) : 0.f;
    float w1 = valid ? __expf(p1 * INV_SQRT_CH) : 0.f;
    float vf[8];
    unpack8_fp8(vw0, vf);
    s0 += w0;
#pragma unroll
    for (int c = 0; c < 8; ++c) a0[c] = fmaf(w0, vf[c], a0[c]);
    unpack8_fp8(vw1, vf);
    s1 += w1;
#pragma unroll
    for (int c = 0; c < 8; ++c) a1[c] = fmaf(w1, vf[c], a1[c]);
  }
#pragma unroll
  for (int ox = 16; ox <= 32; ox <<= 1) {
    s0 += __shfl_xor(s0, ox);
    s1 += __shfl_xor(s1, ox);
#pragma unroll
    for (int c = 0; c < 8; ++c) {
      a0[c] += __shfl_xor(a0[c], ox);
      a1[c] += __shfl_xor(a1[c], ox);
    }
  }
  if (g != 0) return;
  float inv0 = 0.25f / (s0 + 1e-16f), inv1 = 0.25f / (s1 + 1e-16f);
  uint4 ow;
  uint_t* op = (uint_t*)&ow;
#pragma unroll
  for (int c = 0; c < 4; ++c) {
    float o0 = a0[2 * c] * inv0 + a1[2 * c] * inv1;
    float o1 = a0[2 * c + 1] * inv0 + a1[2 * c + 1] * inv1;
    op[c] = (uint_t)f2bf(o0) | ((uint_t)f2bf(o1) << 16);
  }
  *(uint4*)(PairOut + ((size_t)p * N_NODES + i) * CH + li * 8) = ow;
}

// ---------------------------------------------------------------------------
// Fused pool + ELU + classifier + log_softmax. One block of 256 per graph.
// h2[i][c] = elu(skip(BIG@2048) + PairOut0 + PairOut1).
// ---------------------------------------------------------------------------
__global__ __launch_bounds__(256) void pool_cls(
    const ushort_t* __restrict__ PairOut, const char* __restrict__ BIG,
    const int* __restrict__ gstart, const int* __restrict__ gend,
    const float* __restrict__ Wfc, const float* __restrict__ bfc,
    float* __restrict__ out) {
  int g = blockIdx.x;
  int t = threadIdx.x;
  int c = t & (CH - 1), rr = t >> 7;
  int s0 = gstart[g], e0 = gend[g];
  const ushort_t* P1 = PairOut + (size_t)N_NODES * CH;
  float sum = 0.f;
  for (int i = s0 + rr; i < e0; i += 2) {
    float sk = bf2f(*(const ushort_t*)(BIG + (size_t)i * 2304 + 2048 + c * 2));
    float m0 = bf2f(PairOut[(size_t)i * CH + c]);
    float m1 = bf2f(P1[(size_t)i * CH + c]);
    float v = sk + m0 + m1;
    v = v > 0.f ? v : expm1f(v);
    sum += v;
  }
  __shared__ float sh[256];
  __shared__ float p[CH];
  __shared__ float red[CH];
  __shared__ float logits[NCLS];
  sh[t] = sum;
  __syncthreads();
  if (t < CH) {
    float cnt = fmaxf((float)(e0 - s0), 1.f);
    p[t] = (sh[t] + sh[t + CH]) / cnt;
  }
  for (int cc = 0; cc < NCLS; ++cc) {
    __syncthreads();
    if (t < CH) red[t] = p[t] * Wfc[t * NCLS + cc];
    __syncthreads();
    for (int off = 64; off > 0; off >>= 1) {
      if (t < off) red[t] += red[t + off];
      __syncthreads();
    }
    if (t == 0) logits[cc] = red[0] + bfc[cc];
  }
  __syncthreads();
  if (t == 0) {
    float mx = -INFINITY;
    for (int cc = 0; cc < NCLS; ++cc) mx = fmaxf(mx, logits[cc]);
    float se = 0.f;
    for (int cc = 0; cc < NCLS; ++cc) se += expf(logits[cc] - mx);
    float ls = mx + logf(se);
    for (int cc = 0; cc < NCLS; ++cc) out[g * NCLS + cc] = logits[cc] - ls;
  }
}

// ---------------------------------------------------------------------------
extern "C" void kernel_launch(void* const* d_in, const int* in_sizes, int n_in,
                              void* d_out, int out_size, void* d_ws, size_t ws_size,
                              hipStream_t stream) {
  const float* x    = (const float*)d_in[0];
  const int*   ei   = (const int*)d_in[1];
  const int*   batch= (const int*)d_in[2];
  const float* Wq1 = (const float*)d_in[3];  const float* bq1 = (const float*)d_in[4];
  const float* Wk1 = (const float*)d_in[5];  const float* bk1 = (const float*)d_in[6];
  const float* Wv1 = (const float*)d_in[7];  const float* bv1 = (const float*)d_in[8];
  const float* Ws1 = (const float*)d_in[9];  const float* bs1 = (const float*)d_in[10];
  const float* Wq2 = (const float*)d_in[11]; const float* bq2 = (const float*)d_in[12];
  const float* Wk2 = (const float*)d_in[13]; const float* bk2 = (const float*)d_in[14];
  const float* Wv2 = (const float*)d_in[15]; const float* bv2 = (const float*)d_in[16];
  const float* Ws2 = (const float*)d_in[17]; const float* bs2 = (const float*)d_in[18];
  const float* Wfc = (const float*)d_in[19]; const float* bfc = (const float*)d_in[20];
  float* out = (float*)d_out;

  // Workspace (~195 MB). PairOut (bf16 2*N*128 = 25.6MB) aliases xb (dead
  // after L1 GEMMs). BIG sized for L2's 2304 B rows; L1 uses stride 1536.
  ushort_t* xb     = (ushort_t*)d_ws;                   // N x 256 bf16 (25.6 MB)
  ushort_t* PairOut= (ushort_t*)d_ws;                   // 2 x N x 128 bf16 (alias)
  char*     BIG    = (char*)(xb + (size_t)N_NODES * FEAT);  // N x 2304 B (115.2 MB)
  ushort_t* H1b    = (ushort_t*)(BIG + (size_t)N_NODES * 2304); // N x 512 bf16
  ushort_t* W1t    = H1b + (size_t)N_NODES * HID;       // 2048*256
  float*    Bh1    = (float*)(W1t + L1_W);              // 2048
  ushort_t* W2t    = (ushort_t*)(Bh1 + 2048);           // 1664*512
  float*    Bh2    = (float*)(W2t + L2_W);              // 1664
  int* deg    = (int*)(Bh2 + 1664);
  int* start  = deg + N_NODES;
  int* cursor = start + N_NODES;
  int* csr    = cursor + N_NODES;
  int* gstart = csr + EDGES;
  int* gend   = gstart + NGRAPH;
  int* counter= gend + NGRAPH;

  const int* srcp = ei;
  const int* dstp = ei + EDGES;

  // ---- prep (single launch) + CSR build ----
  prep_all<<<NB_CVT + NB_TP + NB_BIAS + NB_ZERO, 256, 0, stream>>>(
      x, xb, Wq1, Wk1, Wv1, Ws1, Wq2, Wk2, Wv2, Ws2,
      bq1, bk1, bv1, bs1, bq2, bk2, bv2, bs2,
      W1t, W2t, Bh1, Bh2, deg, counter, gstart, gend);
  hist_bounds_kernel<<<(EDGES + 255) / 256, 256, 0, stream>>>(dstp, deg, batch, gstart, gend);
  alloc_kernel<<<(N_NODES + 255) / 256, 256, 0, stream>>>(deg, counter, start, cursor);
  scatter_kernel<<<(EDGES + 255) / 256, 256, 0, stream>>>(srcp, dstp, cursor, csr);

  const int gx8 = 49 * 8;               // 392 row tiles (padded; kernel guards)
  const int ga = (N_NODES + 3) / 4;     // 12500

  // ---- layer 1: per head-pair, GEMM (1024 cols, mode 1) + attention ----
  for (int p = 0; p < 2; ++p) {
    gemm_bt<<<gx8 * 8, 256, 0, stream>>>(
        xb, W1t + (size_t)p * 1024 * FEAT, Bh1 + p * 1024, BIG, N_NODES, FEAT, 8, 1);
    attn1_kernel<<<dim3(ga, 2), 256, 0, stream>>>(BIG, start, deg, csr, H1b, p);
  }

  // ---- layer 2: ONE GEMM (all 4 heads + skip, 1664 cols) + ONE attention ----
  gemm_bt<<<gx8 * 13, 256, 0, stream>>>(
      H1b, W2t, Bh2, BIG, N_NODES, HID, 13, 2);
  attn2_kernel<<<dim3(ga, 2), 256, 0, stream>>>(BIG, start, deg, csr, PairOut);

  // ---- fused pool + classify ----
  pool_cls<<<NGRAPH, 256, 0, stream>>>(PairOut, BIG, gstart, gend, Wfc, bfc, out);
}